// Round 1
// baseline (644.744 us; speedup 1.0000x reference)
//
#include <hip/hip_runtime.h>

// ---------------- CSR build ----------------

__global__ void deg_kernel(const int* __restrict__ row, int* __restrict__ deg, int E) {
  int e = blockIdx.x * blockDim.x + threadIdx.x;
  if (e < E) atomicAdd(&deg[row[e]], 1);
}

__global__ __launch_bounds__(1024) void scan_block_kernel(
    const int* __restrict__ deg, int* __restrict__ rowptr,
    float* __restrict__ invdeg, int* __restrict__ bsum, int n) {
  __shared__ int s[1024];
  int i = blockIdx.x * 1024 + threadIdx.x;
  int v = (i < n) ? deg[i] : 0;
  if (i < n) invdeg[i] = (v > 0) ? (1.0f / (float)v) : 0.0f;
  s[threadIdx.x] = v;
  __syncthreads();
  for (int off = 1; off < 1024; off <<= 1) {
    int t = (threadIdx.x >= off) ? s[threadIdx.x - off] : 0;
    __syncthreads();
    s[threadIdx.x] += t;
    __syncthreads();
  }
  if (i < n) rowptr[i] = s[threadIdx.x] - v;   // exclusive within block
  if (threadIdx.x == 1023) bsum[blockIdx.x] = s[1023];
}

__global__ void scan_sums_kernel(int* bsum, int nb) {
  // single wave, exclusive scan of block sums
  int lane = threadIdx.x;
  int run = 0;
  for (int base = 0; base < nb; base += 64) {
    int orig = (base + lane < nb) ? bsum[base + lane] : 0;
    int v = orig;
    #pragma unroll
    for (int off = 1; off < 64; off <<= 1) {
      int t = __shfl_up(v, off, 64);
      if (lane >= off) v += t;
    }
    if (base + lane < nb) bsum[base + lane] = run + v - orig;
    run += __shfl(v, 63, 64);
  }
}

__global__ void apply_off_kernel(int* __restrict__ rowptr, const int* __restrict__ bsum,
                                 int* __restrict__ fill, int n, int E) {
  int i = blockIdx.x * blockDim.x + threadIdx.x;
  if (i < n) {
    int v = rowptr[i] + bsum[i >> 10];
    rowptr[i] = v;
    fill[i] = v;
  }
  if (i == 0) rowptr[n] = E;
}

__global__ void fill_kernel(const int* __restrict__ row, const int* __restrict__ col,
                            int* __restrict__ fill, int* __restrict__ colidx, int E) {
  int e = blockIdx.x * blockDim.x + threadIdx.x;
  if (e < E) {
    int p = atomicAdd(&fill[row[e]], 1);
    colidx[p] = col[e];
  }
}

// ---------------- mean aggregation: one wave per node ----------------

__global__ __launch_bounds__(256) void agg_kernel(
    const float* __restrict__ feat, const int* __restrict__ rowptr,
    const int* __restrict__ colidx, const float* __restrict__ invdeg,
    float* __restrict__ out, int n) {
  int node = blockIdx.x * 4 + (threadIdx.x >> 6);
  int lane = threadIdx.x & 63;
  if (node >= n) return;
  int start = rowptr[node], end = rowptr[node + 1];
  float ax = 0.f, ay = 0.f;
  for (int base = start; base < end; base += 64) {
    int cnt = end - base;
    if (cnt > 64) cnt = 64;
    int cidx = (base + lane < end) ? colidx[base + lane] : 0;
    int t = 0;
    for (; t + 4 <= cnt; t += 4) {
      int c0 = __shfl(cidx, t + 0, 64);
      int c1 = __shfl(cidx, t + 1, 64);
      int c2 = __shfl(cidx, t + 2, 64);
      int c3 = __shfl(cidx, t + 3, 64);
      float2 v0 = *(const float2*)(feat + (size_t)c0 * 128 + lane * 2);
      float2 v1 = *(const float2*)(feat + (size_t)c1 * 128 + lane * 2);
      float2 v2 = *(const float2*)(feat + (size_t)c2 * 128 + lane * 2);
      float2 v3 = *(const float2*)(feat + (size_t)c3 * 128 + lane * 2);
      ax += v0.x + v1.x + v2.x + v3.x;
      ay += v0.y + v1.y + v2.y + v3.y;
    }
    for (; t < cnt; ++t) {
      int c = __shfl(cidx, t, 64);
      float2 v = *(const float2*)(feat + (size_t)c * 128 + lane * 2);
      ax += v.x;
      ay += v.y;
    }
  }
  float s = invdeg[node];
  float2 o;
  o.x = ax * s;
  o.y = ay * s;
  *(float2*)(out + (size_t)node * 128 + lane * 2) = o;
}

// ---------------- fused dual-GEMM: C = Aagg@Wn^T + Aroot@Wr^T (+ReLU) ----------------
// K=256 concat. Block: 256 threads, 64 rows. Thread tile: 4 rows x 8 cols.

template <bool RELU>
__global__ __launch_bounds__(256) void fused_gemm_kernel(
    const float* __restrict__ Aagg, const float* __restrict__ Aroot,
    const float* __restrict__ Wn, const float* __restrict__ Wr,
    float* __restrict__ Cout, int nrows) {
  __shared__ float As[32][68];    // [kk][row], padded
  __shared__ float Ws[32][132];   // [kk][j], padded
  const int tid = threadIdx.x;
  const int rg = tid >> 4, cg = tid & 15;
  const int r0 = rg * 4, c0 = cg * 8;
  const int brow = blockIdx.x * 64;
  float acc[4][8];
  #pragma unroll
  for (int i = 0; i < 4; ++i)
    #pragma unroll
    for (int j = 0; j < 8; ++j) acc[i][j] = 0.f;

  for (int k0 = 0; k0 < 256; k0 += 32) {
    const float* Asrc = (k0 < 128) ? Aagg : Aroot;
    const float* Wsrc = (k0 < 128) ? Wn : Wr;
    const int kb = k0 & 127;
    // stage A slice: 64 rows x 32 k (transposed into LDS)
    #pragma unroll
    for (int s = 0; s < 2; ++s) {
      int idx = tid + s * 256;  // 0..511
      int row = idx >> 3, kq = (idx & 7) * 4;
      int grow = brow + row;
      if (grow > nrows - 1) grow = nrows - 1;  // clamp (discarded at store)
      float4 v = *(const float4*)(Asrc + (size_t)grow * 128 + kb + kq);
      As[kq + 0][row] = v.x;
      As[kq + 1][row] = v.y;
      As[kq + 2][row] = v.z;
      As[kq + 3][row] = v.w;
    }
    // stage W slice: 128 j x 32 k (transposed into LDS)
    #pragma unroll
    for (int s = 0; s < 4; ++s) {
      int idx = tid + s * 256;  // 0..1023
      int j = idx >> 3, kq = (idx & 7) * 4;
      float4 v = *(const float4*)(Wsrc + j * 128 + kb + kq);
      Ws[kq + 0][j] = v.x;
      Ws[kq + 1][j] = v.y;
      Ws[kq + 2][j] = v.z;
      Ws[kq + 3][j] = v.w;
    }
    __syncthreads();
    #pragma unroll
    for (int kk = 0; kk < 32; ++kk) {
      float a0 = As[kk][r0 + 0], a1 = As[kk][r0 + 1];
      float a2 = As[kk][r0 + 2], a3 = As[kk][r0 + 3];
      float w[8];
      #pragma unroll
      for (int j = 0; j < 8; ++j) w[j] = Ws[kk][c0 + j];
      #pragma unroll
      for (int j = 0; j < 8; ++j) {
        acc[0][j] = fmaf(a0, w[j], acc[0][j]);
        acc[1][j] = fmaf(a1, w[j], acc[1][j]);
        acc[2][j] = fmaf(a2, w[j], acc[2][j]);
        acc[3][j] = fmaf(a3, w[j], acc[3][j]);
      }
    }
    __syncthreads();
  }
  #pragma unroll
  for (int i = 0; i < 4; ++i) {
    int row = brow + r0 + i;
    if (row < nrows) {
      float o[8];
      #pragma unroll
      for (int j = 0; j < 8; ++j) {
        float v = acc[i][j];
        o[j] = RELU ? fmaxf(v, 0.f) : v;
      }
      *(float4*)(Cout + (size_t)row * 128 + c0) = make_float4(o[0], o[1], o[2], o[3]);
      *(float4*)(Cout + (size_t)row * 128 + c0 + 4) = make_float4(o[4], o[5], o[6], o[7]);
    }
  }
}

// ---------------- launch ----------------

extern "C" void kernel_launch(void* const* d_in, const int* in_sizes, int n_in,
                              void* d_out, int out_size, void* d_ws, size_t ws_size,
                              hipStream_t stream) {
  const float* x = (const float*)d_in[0];
  const float* wn1 = (const float*)d_in[1];
  const float* wr1 = (const float*)d_in[2];
  const float* wn2 = (const float*)d_in[3];
  const float* wr2 = (const float*)d_in[4];
  const int* ei = (const int*)d_in[5];
  const int N = in_sizes[0] / 128;
  const int E = in_sizes[5] / 2;
  const int* row = ei;      // destinations
  const int* col = ei + E;  // sources

  char* p = (char*)d_ws;
  float* H = (float*)p;        p += (size_t)N * 128 * sizeof(float);  // 51.2 MB
  int* colidx = (int*)p;       p += (size_t)E * sizeof(int);          // 6.4 MB
  int* rowptr = (int*)p;       p += (size_t)(N + 1) * sizeof(int);
  int* fill = (int*)p;         p += (size_t)N * sizeof(int);
  int* degi = (int*)p;         p += (size_t)N * sizeof(int);
  float* invdeg = (float*)p;   p += (size_t)N * sizeof(float);
  int* bsum = (int*)p;         p += 1024;
  float* aggbuf = (float*)d_out;  // d_out doubles as aggregation scratch

  // CSR build
  hipMemsetAsync(degi, 0, (size_t)N * sizeof(int), stream);
  deg_kernel<<<(E + 255) / 256, 256, 0, stream>>>(row, degi, E);
  int nb = (N + 1023) / 1024;
  scan_block_kernel<<<nb, 1024, 0, stream>>>(degi, rowptr, invdeg, bsum, N);
  scan_sums_kernel<<<1, 64, 0, stream>>>(bsum, nb);
  apply_off_kernel<<<(N + 255) / 256, 256, 0, stream>>>(rowptr, bsum, fill, N, E);
  fill_kernel<<<(E + 255) / 256, 256, 0, stream>>>(row, col, fill, colidx, E);

  // layer 1: h = relu(agg(x)@Wn1^T + x@Wr1^T)
  agg_kernel<<<(N + 3) / 4, 256, 0, stream>>>(x, rowptr, colidx, invdeg, aggbuf, N);
  fused_gemm_kernel<true><<<(N + 63) / 64, 256, 0, stream>>>(aggbuf, x, wn1, wr1, H, N);

  // layer 2: out = agg(h)@Wn2^T + h@Wr2^T
  agg_kernel<<<(N + 3) / 4, 256, 0, stream>>>(H, rowptr, colidx, invdeg, aggbuf, N);
  fused_gemm_kernel<false><<<(N + 63) / 64, 256, 0, stream>>>(aggbuf, H, wn2, wr2,
                                                              aggbuf, N);
}

// Round 2
// 439.955 us; speedup vs baseline: 1.4655x; 1.4655x over previous
//
#include <hip/hip_runtime.h>

#define NBUK_MAX 512  // buckets of 256 rows; N=100000 -> 391 buckets

static __device__ __forceinline__ float bf2f(unsigned int u16) {
  unsigned int t = u16 << 16;
  return __builtin_bit_cast(float, t);
}
static __device__ __forceinline__ unsigned int f2bf(float f) {
  unsigned int t = __builtin_bit_cast(unsigned int, f);
  t += 0x7fff + ((t >> 16) & 1);
  return t >> 16;
}

// ---------------- CSR build: two-level bucket sort ----------------

__global__ __launch_bounds__(256) void p1a_hist(const int* __restrict__ row,
                                                int* __restrict__ bcount, int E,
                                                int nbuk) {
  __shared__ int h[NBUK_MAX];
  for (int i = threadIdx.x; i < nbuk; i += 256) h[i] = 0;
  __syncthreads();
  int stride = gridDim.x * 256;
  for (int e = blockIdx.x * 256 + threadIdx.x; e < E; e += stride)
    atomicAdd(&h[row[e] >> 8], 1);
  __syncthreads();
  for (int i = threadIdx.x; i < nbuk; i += 256)
    if (h[i]) atomicAdd(&bcount[i], h[i]);
}

__global__ __launch_bounds__(512) void bucket_scan_kernel(
    const int* __restrict__ bcount, int* __restrict__ boff,
    int* __restrict__ bfill, int nbuk, int E) {
  __shared__ int s[512];
  int t = threadIdx.x;
  int v = (t < nbuk) ? bcount[t] : 0;
  s[t] = v;
  __syncthreads();
  for (int off = 1; off < 512; off <<= 1) {
    int u = (t >= off) ? s[t - off] : 0;
    __syncthreads();
    s[t] += u;
    __syncthreads();
  }
  if (t < nbuk) {
    int ex = s[t] - v;
    boff[t] = ex;
    bfill[t] = ex;
  }
  if (t == 0) boff[nbuk] = E;
}

#define P1C_KE 32
__global__ __launch_bounds__(256) void p1c_scatter(
    const int* __restrict__ row, const int* __restrict__ col,
    int* __restrict__ bfill, int* __restrict__ bbuf, int E, int nbuk) {
  __shared__ int cnt[NBUK_MAX];
  __shared__ int base[NBUK_MAX];
  int e0 = blockIdx.x * (256 * P1C_KE);
  for (int i = threadIdx.x; i < nbuk; i += 256) cnt[i] = 0;
  __syncthreads();
  for (int k = 0; k < P1C_KE; ++k) {
    int e = e0 + k * 256 + threadIdx.x;
    if (e < E) atomicAdd(&cnt[row[e] >> 8], 1);
  }
  __syncthreads();
  for (int i = threadIdx.x; i < nbuk; i += 256) {
    int c = cnt[i];
    base[i] = c ? atomicAdd(&bfill[i], c) : 0;
    cnt[i] = 0;
  }
  __syncthreads();
  for (int k = 0; k < P1C_KE; ++k) {
    int e = e0 + k * 256 + threadIdx.x;
    if (e < E) {
      int r = row[e];
      int b = r >> 8;
      int rk = atomicAdd(&cnt[b], 1);
      bbuf[base[b] + rk] = ((r & 255) << 17) | col[e];
    }
  }
}

__global__ __launch_bounds__(256) void p2a_deg(const int* __restrict__ boff,
                                               const int* __restrict__ bbuf,
                                               int* __restrict__ deg,
                                               float* __restrict__ invdeg, int N) {
  __shared__ int cnt[256];
  int b = blockIdx.x;
  cnt[threadIdx.x] = 0;
  __syncthreads();
  int s = boff[b], e = boff[b + 1];
  for (int i = s + threadIdx.x; i < e; i += 256) atomicAdd(&cnt[bbuf[i] >> 17], 1);
  __syncthreads();
  int r = (b << 8) + threadIdx.x;
  if (r < N) {
    int c = cnt[threadIdx.x];
    deg[r] = c;
    invdeg[r] = c ? 1.0f / (float)c : 0.0f;
  }
}

__global__ __launch_bounds__(1024) void scan_block_kernel(
    const int* __restrict__ deg, int* __restrict__ rowptr, int* __restrict__ bsum,
    int n) {
  __shared__ int s[1024];
  int i = blockIdx.x * 1024 + threadIdx.x;
  int v = (i < n) ? deg[i] : 0;
  s[threadIdx.x] = v;
  __syncthreads();
  for (int off = 1; off < 1024; off <<= 1) {
    int t = (threadIdx.x >= off) ? s[threadIdx.x - off] : 0;
    __syncthreads();
    s[threadIdx.x] += t;
    __syncthreads();
  }
  if (i < n) rowptr[i] = s[threadIdx.x] - v;  // exclusive within block
  if (threadIdx.x == 1023) bsum[blockIdx.x] = s[1023];
}

__global__ void scan_sums_kernel(int* bsum, int nb) {
  int lane = threadIdx.x;
  int run = 0;
  for (int base = 0; base < nb; base += 64) {
    int orig = (base + lane < nb) ? bsum[base + lane] : 0;
    int v = orig;
    #pragma unroll
    for (int off = 1; off < 64; off <<= 1) {
      int t = __shfl_up(v, off, 64);
      if (lane >= off) v += t;
    }
    if (base + lane < nb) bsum[base + lane] = run + v - orig;
    run += __shfl(v, 63, 64);
  }
}

__global__ void apply_off_kernel(int* __restrict__ rowptr,
                                 const int* __restrict__ bsum, int n, int E) {
  int i = blockIdx.x * blockDim.x + threadIdx.x;
  if (i < n) rowptr[i] += bsum[i >> 10];
  if (i == 0) rowptr[n] = E;
}

__global__ __launch_bounds__(256) void p2b_place(const int* __restrict__ boff,
                                                 const int* __restrict__ bbuf,
                                                 const int* __restrict__ rowptr,
                                                 int* __restrict__ colidx, int N) {
  __shared__ int rbase[256];
  __shared__ int cnt[256];
  int b = blockIdx.x;
  int r = (b << 8) + threadIdx.x;
  rbase[threadIdx.x] = (r < N) ? rowptr[r] : 0;
  cnt[threadIdx.x] = 0;
  __syncthreads();
  int s = boff[b], e = boff[b + 1];
  for (int i = s + threadIdx.x; i < e; i += 256) {
    int p = bbuf[i];
    int rl = p >> 17;
    int k = atomicAdd(&cnt[rl], 1);
    colidx[rbase[rl] + k] = p & 0x1FFFF;
  }
}

// ---------------- f32 -> bf16 conversion ----------------

__global__ __launch_bounds__(256) void tobf16_kernel(const float* __restrict__ in,
                                                     unsigned short* __restrict__ out,
                                                     long n4) {
  long i = (long)blockIdx.x * 256 + threadIdx.x;
  long stride = (long)gridDim.x * 256;
  for (; i < n4; i += stride) {
    float4 v = ((const float4*)in)[i];
    ushort4 o;
    o.x = (unsigned short)f2bf(v.x);
    o.y = (unsigned short)f2bf(v.y);
    o.z = (unsigned short)f2bf(v.z);
    o.w = (unsigned short)f2bf(v.w);
    ((ushort4*)out)[i] = o;
  }
}

// ---------------- mean aggregation (bf16 gather, f32 accum) ----------------

__global__ __launch_bounds__(256) void agg_bf16_kernel(
    const unsigned short* __restrict__ feat, const int* __restrict__ rowptr,
    const int* __restrict__ colidx, const float* __restrict__ invdeg,
    float* __restrict__ out, int n) {
  int node = blockIdx.x * 4 + (threadIdx.x >> 6);
  int lane = threadIdx.x & 63;
  if (node >= n) return;
  int start = rowptr[node], end = rowptr[node + 1];
  float ax = 0.f, ay = 0.f;
  for (int base = start; base < end; base += 64) {
    int cnt = end - base;
    if (cnt > 64) cnt = 64;
    int cidx = (base + lane < end) ? colidx[base + lane] : 0;
    int t = 0;
    for (; t + 4 <= cnt; t += 4) {
      int c0 = __shfl(cidx, t + 0, 64);
      int c1 = __shfl(cidx, t + 1, 64);
      int c2 = __shfl(cidx, t + 2, 64);
      int c3 = __shfl(cidx, t + 3, 64);
      unsigned int v0 = *(const unsigned int*)(feat + (size_t)c0 * 128 + lane * 2);
      unsigned int v1 = *(const unsigned int*)(feat + (size_t)c1 * 128 + lane * 2);
      unsigned int v2 = *(const unsigned int*)(feat + (size_t)c2 * 128 + lane * 2);
      unsigned int v3 = *(const unsigned int*)(feat + (size_t)c3 * 128 + lane * 2);
      ax += bf2f(v0 & 0xffff) + bf2f(v1 & 0xffff) + bf2f(v2 & 0xffff) +
            bf2f(v3 & 0xffff);
      ay += bf2f(v0 >> 16) + bf2f(v1 >> 16) + bf2f(v2 >> 16) + bf2f(v3 >> 16);
    }
    for (; t < cnt; ++t) {
      int c = __shfl(cidx, t, 64);
      unsigned int v = *(const unsigned int*)(feat + (size_t)c * 128 + lane * 2);
      ax += bf2f(v & 0xffff);
      ay += bf2f(v >> 16);
    }
  }
  float s = invdeg[node];
  float2 o;
  o.x = ax * s;
  o.y = ay * s;
  *(float2*)(out + (size_t)node * 128 + lane * 2) = o;
}

// ---------------- fused dual-GEMM: C = Aagg@Wn^T + Aroot@Wr^T (+ReLU) ----------------
// K=256 concat. Block: 256 threads, 64 rows. Thread tile: 4 rows x 8 cols.

template <bool RELU, bool ROOT_BF16, bool OUT_BF16>
__global__ __launch_bounds__(256) void fused_gemm_kernel(
    const float* __restrict__ Aagg, const void* __restrict__ Aroot,
    const float* __restrict__ Wn, const float* __restrict__ Wr,
    void* __restrict__ Cout, int nrows) {
  __shared__ float As[32][68];    // [kk][row], padded
  __shared__ float Ws[32][132];   // [kk][j], padded
  const int tid = threadIdx.x;
  const int rg = tid >> 4, cg = tid & 15;
  const int r0 = rg * 4, c0 = cg * 8;
  const int brow = blockIdx.x * 64;
  float acc[4][8];
  #pragma unroll
  for (int i = 0; i < 4; ++i)
    #pragma unroll
    for (int j = 0; j < 8; ++j) acc[i][j] = 0.f;

  for (int k0 = 0; k0 < 256; k0 += 32) {
    const float* Wsrc = (k0 < 128) ? Wn : Wr;
    const int kb = k0 & 127;
    // stage A slice: 64 rows x 32 k (transposed into LDS)
    #pragma unroll
    for (int s = 0; s < 2; ++s) {
      int idx = tid + s * 256;  // 0..511
      int rw = idx >> 3, kq = (idx & 7) * 4;
      int grow = brow + rw;
      if (grow > nrows - 1) grow = nrows - 1;  // clamp (discarded at store)
      if (k0 < 128) {
        float4 v = *(const float4*)(Aagg + (size_t)grow * 128 + kb + kq);
        As[kq + 0][rw] = v.x;
        As[kq + 1][rw] = v.y;
        As[kq + 2][rw] = v.z;
        As[kq + 3][rw] = v.w;
      } else if (ROOT_BF16) {
        const unsigned short* R = (const unsigned short*)Aroot;
        uint2 v = *(const uint2*)(R + (size_t)grow * 128 + kb + kq);
        As[kq + 0][rw] = bf2f(v.x & 0xffff);
        As[kq + 1][rw] = bf2f(v.x >> 16);
        As[kq + 2][rw] = bf2f(v.y & 0xffff);
        As[kq + 3][rw] = bf2f(v.y >> 16);
      } else {
        const float* R = (const float*)Aroot;
        float4 v = *(const float4*)(R + (size_t)grow * 128 + kb + kq);
        As[kq + 0][rw] = v.x;
        As[kq + 1][rw] = v.y;
        As[kq + 2][rw] = v.z;
        As[kq + 3][rw] = v.w;
      }
    }
    // stage W slice: 128 j x 32 k (transposed into LDS)
    #pragma unroll
    for (int s = 0; s < 4; ++s) {
      int idx = tid + s * 256;  // 0..1023
      int j = idx >> 3, kq = (idx & 7) * 4;
      float4 v = *(const float4*)(Wsrc + j * 128 + kb + kq);
      Ws[kq + 0][j] = v.x;
      Ws[kq + 1][j] = v.y;
      Ws[kq + 2][j] = v.z;
      Ws[kq + 3][j] = v.w;
    }
    __syncthreads();
    #pragma unroll
    for (int kk = 0; kk < 32; ++kk) {
      float a0 = As[kk][r0 + 0], a1 = As[kk][r0 + 1];
      float a2 = As[kk][r0 + 2], a3 = As[kk][r0 + 3];
      float w[8];
      #pragma unroll
      for (int j = 0; j < 8; ++j) w[j] = Ws[kk][c0 + j];
      #pragma unroll
      for (int j = 0; j < 8; ++j) {
        acc[0][j] = fmaf(a0, w[j], acc[0][j]);
        acc[1][j] = fmaf(a1, w[j], acc[1][j]);
        acc[2][j] = fmaf(a2, w[j], acc[2][j]);
        acc[3][j] = fmaf(a3, w[j], acc[3][j]);
      }
    }
    __syncthreads();
  }
  #pragma unroll
  for (int i = 0; i < 4; ++i) {
    int row = brow + r0 + i;
    if (row < nrows) {
      float o[8];
      #pragma unroll
      for (int j = 0; j < 8; ++j) {
        float v = acc[i][j];
        o[j] = RELU ? fmaxf(v, 0.f) : v;
      }
      if (OUT_BF16) {
        unsigned short* O = (unsigned short*)Cout;
        uint4 pk;
        pk.x = f2bf(o[0]) | (f2bf(o[1]) << 16);
        pk.y = f2bf(o[2]) | (f2bf(o[3]) << 16);
        pk.z = f2bf(o[4]) | (f2bf(o[5]) << 16);
        pk.w = f2bf(o[6]) | (f2bf(o[7]) << 16);
        *(uint4*)(O + (size_t)row * 128 + c0) = pk;
      } else {
        float* O = (float*)Cout;
        *(float4*)(O + (size_t)row * 128 + c0) = make_float4(o[0], o[1], o[2], o[3]);
        *(float4*)(O + (size_t)row * 128 + c0 + 4) =
            make_float4(o[4], o[5], o[6], o[7]);
      }
    }
  }
}

// ---------------- launch ----------------

extern "C" void kernel_launch(void* const* d_in, const int* in_sizes, int n_in,
                              void* d_out, int out_size, void* d_ws, size_t ws_size,
                              hipStream_t stream) {
  const float* x = (const float*)d_in[0];
  const float* wn1 = (const float*)d_in[1];
  const float* wr1 = (const float*)d_in[2];
  const float* wn2 = (const float*)d_in[3];
  const float* wr2 = (const float*)d_in[4];
  const int* ei = (const int*)d_in[5];
  const int N = in_sizes[0] / 128;
  const int E = in_sizes[5] / 2;
  const int* row = ei;      // destinations
  const int* col = ei + E;  // sources
  const int NBUK = (N + 255) >> 8;

  char* p = (char*)d_ws;
  unsigned short* Xb = (unsigned short*)p;  p += (size_t)N * 128 * 2;  // 25.6 MB
  unsigned short* Hb = (unsigned short*)p;  p += (size_t)N * 128 * 2;  // 25.6 MB
  int* bbuf = (int*)p;      p += (size_t)E * 4;                        // 6.4 MB
  int* colidx = (int*)p;    p += (size_t)E * 4;                        // 6.4 MB
  int* rowptr = (int*)p;    p += (size_t)(N + 1) * 4;
  int* deg = (int*)p;       p += (size_t)N * 4;
  float* invdeg = (float*)p; p += (size_t)N * 4;
  int* bcount = (int*)p;    p += NBUK_MAX * 4;
  int* boff = (int*)p;      p += (NBUK_MAX + 1) * 4;
  int* bfill = (int*)p;     p += NBUK_MAX * 4;
  int* bsum = (int*)p;      p += 1024;
  float* aggbuf = (float*)d_out;  // d_out doubles as aggregation scratch

  // --- CSR build (two-level bucket sort) ---
  hipMemsetAsync(bcount, 0, NBUK * 4, stream);
  p1a_hist<<<256, 256, 0, stream>>>(row, bcount, E, NBUK);
  bucket_scan_kernel<<<1, 512, 0, stream>>>(bcount, boff, bfill, NBUK, E);
  p1c_scatter<<<(E + 256 * P1C_KE - 1) / (256 * P1C_KE), 256, 0, stream>>>(
      row, col, bfill, bbuf, E, NBUK);
  p2a_deg<<<NBUK, 256, 0, stream>>>(boff, bbuf, deg, invdeg, N);
  int nb = (N + 1023) / 1024;
  scan_block_kernel<<<nb, 1024, 0, stream>>>(deg, rowptr, bsum, N);
  scan_sums_kernel<<<1, 64, 0, stream>>>(bsum, nb);
  apply_off_kernel<<<(N + 255) / 256, 256, 0, stream>>>(rowptr, bsum, N, E);
  p2b_place<<<NBUK, 256, 0, stream>>>(boff, bbuf, rowptr, colidx, N);

  // --- x -> bf16 ---
  tobf16_kernel<<<2048, 256, 0, stream>>>(x, Xb, (long)N * 32);

  // --- layer 1: h = relu(agg(x)@Wn1^T + x@Wr1^T), stored bf16 ---
  agg_bf16_kernel<<<(N + 3) / 4, 256, 0, stream>>>(Xb, rowptr, colidx, invdeg,
                                                   aggbuf, N);
  fused_gemm_kernel<true, false, true><<<(N + 63) / 64, 256, 0, stream>>>(
      aggbuf, x, wn1, wr1, Hb, N);

  // --- layer 2: out = agg(h)@Wn2^T + h@Wr2^T ---
  agg_bf16_kernel<<<(N + 3) / 4, 256, 0, stream>>>(Hb, rowptr, colidx, invdeg,
                                                   aggbuf, N);
  fused_gemm_kernel<false, true, false><<<(N + 63) / 64, 256, 0, stream>>>(
      aggbuf, Hb, wn2, wr2, (void*)aggbuf, N);
}

// Round 3
// 349.754 us; speedup vs baseline: 1.8434x; 1.2579x over previous
//
#include <hip/hip_runtime.h>

#define NBUK_MAX 512  // buckets of 256 rows; N=100000 -> 391 buckets

typedef __attribute__((ext_vector_type(8))) short bf16x8;
typedef __attribute__((ext_vector_type(4))) float f32x4;

static __device__ __forceinline__ float bf2f(unsigned int u16) {
  unsigned int t = u16 << 16;
  return __builtin_bit_cast(float, t);
}
static __device__ __forceinline__ unsigned int f2bf(float f) {
  unsigned int t = __builtin_bit_cast(unsigned int, f);
  t += 0x7fff + ((t >> 16) & 1);
  return t >> 16;
}

// ---------------- CSR build: two-level bucket sort ----------------

__global__ __launch_bounds__(256) void p1a_hist(const int* __restrict__ row,
                                                int* __restrict__ bcount, int E,
                                                int nbuk) {
  __shared__ int h[NBUK_MAX];
  for (int i = threadIdx.x; i < nbuk; i += 256) h[i] = 0;
  __syncthreads();
  int stride = gridDim.x * 256;
  for (int e = blockIdx.x * 256 + threadIdx.x; e < E; e += stride)
    atomicAdd(&h[row[e] >> 8], 1);
  __syncthreads();
  for (int i = threadIdx.x; i < nbuk; i += 256)
    if (h[i]) atomicAdd(&bcount[i], h[i]);
}

__global__ __launch_bounds__(512) void bucket_scan_kernel(
    const int* __restrict__ bcount, int* __restrict__ boff,
    int* __restrict__ bfill, int nbuk, int E) {
  __shared__ int s[512];
  int t = threadIdx.x;
  int v = (t < nbuk) ? bcount[t] : 0;
  s[t] = v;
  __syncthreads();
  for (int off = 1; off < 512; off <<= 1) {
    int u = (t >= off) ? s[t - off] : 0;
    __syncthreads();
    s[t] += u;
    __syncthreads();
  }
  if (t < nbuk) {
    int ex = s[t] - v;
    boff[t] = ex;
    bfill[t] = ex;
  }
  if (t == 0) boff[nbuk] = E;
}

#define P1C_KE 32
__global__ __launch_bounds__(256) void p1c_scatter(
    const int* __restrict__ row, const int* __restrict__ col,
    int* __restrict__ bfill, int* __restrict__ bbuf, int E, int nbuk) {
  __shared__ int cnt[NBUK_MAX];
  __shared__ int base[NBUK_MAX];
  int e0 = blockIdx.x * (256 * P1C_KE);
  for (int i = threadIdx.x; i < nbuk; i += 256) cnt[i] = 0;
  __syncthreads();
  for (int k = 0; k < P1C_KE; ++k) {
    int e = e0 + k * 256 + threadIdx.x;
    if (e < E) atomicAdd(&cnt[row[e] >> 8], 1);
  }
  __syncthreads();
  for (int i = threadIdx.x; i < nbuk; i += 256) {
    int c = cnt[i];
    base[i] = c ? atomicAdd(&bfill[i], c) : 0;
    cnt[i] = 0;
  }
  __syncthreads();
  for (int k = 0; k < P1C_KE; ++k) {
    int e = e0 + k * 256 + threadIdx.x;
    if (e < E) {
      int r = row[e];
      int b = r >> 8;
      int rk = atomicAdd(&cnt[b], 1);
      bbuf[base[b] + rk] = ((r & 255) << 17) | col[e];
    }
  }
}

__global__ __launch_bounds__(256) void p2a_deg(const int* __restrict__ boff,
                                               const int* __restrict__ bbuf,
                                               int* __restrict__ deg,
                                               float* __restrict__ invdeg, int N) {
  __shared__ int cnt[256];
  int b = blockIdx.x;
  cnt[threadIdx.x] = 0;
  __syncthreads();
  int s = boff[b], e = boff[b + 1];
  for (int i = s + threadIdx.x; i < e; i += 256) atomicAdd(&cnt[bbuf[i] >> 17], 1);
  __syncthreads();
  int r = (b << 8) + threadIdx.x;
  if (r < N) {
    int c = cnt[threadIdx.x];
    deg[r] = c;
    invdeg[r] = c ? 1.0f / (float)c : 0.0f;
  }
}

__global__ __launch_bounds__(1024) void scan_block_kernel(
    const int* __restrict__ deg, int* __restrict__ rowptr, int* __restrict__ bsum,
    int n) {
  __shared__ int s[1024];
  int i = blockIdx.x * 1024 + threadIdx.x;
  int v = (i < n) ? deg[i] : 0;
  s[threadIdx.x] = v;
  __syncthreads();
  for (int off = 1; off < 1024; off <<= 1) {
    int t = (threadIdx.x >= off) ? s[threadIdx.x - off] : 0;
    __syncthreads();
    s[threadIdx.x] += t;
    __syncthreads();
  }
  if (i < n) rowptr[i] = s[threadIdx.x] - v;  // exclusive within block
  if (threadIdx.x == 1023) bsum[blockIdx.x] = s[1023];
}

__global__ void scan_sums_kernel(int* bsum, int nb) {
  int lane = threadIdx.x;
  int run = 0;
  for (int base = 0; base < nb; base += 64) {
    int orig = (base + lane < nb) ? bsum[base + lane] : 0;
    int v = orig;
    #pragma unroll
    for (int off = 1; off < 64; off <<= 1) {
      int t = __shfl_up(v, off, 64);
      if (lane >= off) v += t;
    }
    if (base + lane < nb) bsum[base + lane] = run + v - orig;
    run += __shfl(v, 63, 64);
  }
}

__global__ void apply_off_kernel(int* __restrict__ rowptr,
                                 const int* __restrict__ bsum, int n, int E) {
  int i = blockIdx.x * blockDim.x + threadIdx.x;
  if (i < n) rowptr[i] += bsum[i >> 10];
  if (i == 0) rowptr[n] = E;
}

__global__ __launch_bounds__(256) void p2b_place(const int* __restrict__ boff,
                                                 const int* __restrict__ bbuf,
                                                 const int* __restrict__ rowptr,
                                                 int* __restrict__ colidx, int N) {
  __shared__ int rbase[256];
  __shared__ int cnt[256];
  int b = blockIdx.x;
  int r = (b << 8) + threadIdx.x;
  rbase[threadIdx.x] = (r < N) ? rowptr[r] : 0;
  cnt[threadIdx.x] = 0;
  __syncthreads();
  int s = boff[b], e = boff[b + 1];
  for (int i = s + threadIdx.x; i < e; i += 256) {
    int p = bbuf[i];
    int rl = p >> 17;
    int k = atomicAdd(&cnt[rl], 1);
    colidx[rbase[rl] + k] = p & 0x1FFFF;
  }
}

// ---------------- conversions ----------------

__global__ __launch_bounds__(256) void tobf16_kernel(const float* __restrict__ in,
                                                     unsigned short* __restrict__ out,
                                                     long n4) {
  long i = (long)blockIdx.x * 256 + threadIdx.x;
  long stride = (long)gridDim.x * 256;
  for (; i < n4; i += stride) {
    float4 v = ((const float4*)in)[i];
    ushort4 o;
    o.x = (unsigned short)f2bf(v.x);
    o.y = (unsigned short)f2bf(v.y);
    o.z = (unsigned short)f2bf(v.z);
    o.w = (unsigned short)f2bf(v.w);
    ((ushort4*)out)[i] = o;
  }
}

// 4 weight matrices [128][128] f32 -> bf16, concatenated
__global__ __launch_bounds__(256) void wconv_kernel(
    const float* __restrict__ w0, const float* __restrict__ w1,
    const float* __restrict__ w2, const float* __restrict__ w3,
    unsigned short* __restrict__ out) {
  int i = blockIdx.x * 256 + threadIdx.x;  // 0..65535
  int m = i >> 14, r = i & 16383;
  const float* src = (m == 0) ? w0 : (m == 1) ? w1 : (m == 2) ? w2 : w3;
  out[i] = (unsigned short)f2bf(src[r]);
}

// ---------------- mean aggregation (bf16 gather, f32 accum, f32 out) ----------------

__global__ __launch_bounds__(256) void agg_bf16_kernel(
    const unsigned short* __restrict__ feat, const int* __restrict__ rowptr,
    const int* __restrict__ colidx, const float* __restrict__ invdeg,
    float* __restrict__ out, int n) {
  int node = blockIdx.x * 4 + (threadIdx.x >> 6);
  int lane = threadIdx.x & 63;
  if (node >= n) return;
  int start = rowptr[node], end = rowptr[node + 1];
  float ax = 0.f, ay = 0.f;
  for (int base = start; base < end; base += 64) {
    int cnt = end - base;
    if (cnt > 64) cnt = 64;
    int cidx = (base + lane < end) ? colidx[base + lane] : 0;
    int t = 0;
    for (; t + 4 <= cnt; t += 4) {
      int c0 = __shfl(cidx, t + 0, 64);
      int c1 = __shfl(cidx, t + 1, 64);
      int c2 = __shfl(cidx, t + 2, 64);
      int c3 = __shfl(cidx, t + 3, 64);
      unsigned int v0 = *(const unsigned int*)(feat + (size_t)c0 * 128 + lane * 2);
      unsigned int v1 = *(const unsigned int*)(feat + (size_t)c1 * 128 + lane * 2);
      unsigned int v2 = *(const unsigned int*)(feat + (size_t)c2 * 128 + lane * 2);
      unsigned int v3 = *(const unsigned int*)(feat + (size_t)c3 * 128 + lane * 2);
      ax += bf2f(v0 & 0xffff) + bf2f(v1 & 0xffff) + bf2f(v2 & 0xffff) +
            bf2f(v3 & 0xffff);
      ay += bf2f(v0 >> 16) + bf2f(v1 >> 16) + bf2f(v2 >> 16) + bf2f(v3 >> 16);
    }
    for (; t < cnt; ++t) {
      int c = __shfl(cidx, t, 64);
      unsigned int v = *(const unsigned int*)(feat + (size_t)c * 128 + lane * 2);
      ax += bf2f(v & 0xffff);
      ay += bf2f(v >> 16);
    }
  }
  float s = invdeg[node];
  float2 o;
  o.x = ax * s;
  o.y = ay * s;
  *(float2*)(out + (size_t)node * 128 + lane * 2) = o;
}

// ---------------- MFMA dual-GEMM: C = Aagg@Wn^T + Aroot@Wr^T (+ReLU) ----------------
// Block: 256 thr = 4 waves; block tile 64 rows x 128 cols; wave tile 16x128.
// mfma_f32_16x16x32_bf16 fragments loaded straight from global (no LDS).
// A-frag: lane reads A[m=(lane&15)][k=(lane>>4)*8 + 0..7] (16B).
// B-frag: W is [out_f][in_f] row-major == B^T; lane reads W[n=(lane&15)][k...].
// C/D: col = lane&15, row = (lane>>4)*4 + reg  (verified m89/m91 mapping).

template <bool RELU, bool OUT_BF16>
__global__ __launch_bounds__(256) void mfma_gemm_kernel(
    const float* __restrict__ Aagg,            // f32  [nrows][128]
    const unsigned short* __restrict__ Aroot,  // bf16 [nrows][128]
    const unsigned short* __restrict__ Wn,     // bf16 [128][128]
    const unsigned short* __restrict__ Wr,     // bf16 [128][128]
    void* __restrict__ Cout, int nrows) {
  const int lane = threadIdx.x & 63;
  const int wid = threadIdx.x >> 6;
  const int row0 = blockIdx.x * 64 + wid * 16;
  const int m = lane & 15;
  const int kgrp = lane >> 4;  // 0..3
  int arow = row0 + m;
  if (arow > nrows - 1) arow = nrows - 1;  // clamp; stores masked

  f32x4 acc[8];
  #pragma unroll
  for (int i = 0; i < 8; ++i) acc[i] = (f32x4){0.f, 0.f, 0.f, 0.f};

  #pragma unroll
  for (int ks = 0; ks < 8; ++ks) {
    const int kk = (ks & 3) * 32 + kgrp * 8;
    bf16x8 a;
    if (ks < 4) {
      const float* src = Aagg + (size_t)arow * 128 + kk;
      float4 v0 = *(const float4*)(src);
      float4 v1 = *(const float4*)(src + 4);
      a[0] = (short)f2bf(v0.x);
      a[1] = (short)f2bf(v0.y);
      a[2] = (short)f2bf(v0.z);
      a[3] = (short)f2bf(v0.w);
      a[4] = (short)f2bf(v1.x);
      a[5] = (short)f2bf(v1.y);
      a[6] = (short)f2bf(v1.z);
      a[7] = (short)f2bf(v1.w);
    } else {
      a = *(const bf16x8*)(Aroot + (size_t)arow * 128 + kk);
    }
    const unsigned short* wp = ((ks < 4) ? Wn : Wr) + (size_t)m * 128 + kk;
    #pragma unroll
    for (int nf = 0; nf < 8; ++nf) {
      bf16x8 b = *(const bf16x8*)(wp + nf * 16 * 128);
      acc[nf] = __builtin_amdgcn_mfma_f32_16x16x32_bf16(a, b, acc[nf], 0, 0, 0);
    }
  }

  const int crow0 = row0 + kgrp * 4;
  #pragma unroll
  for (int nf = 0; nf < 8; ++nf) {
    int col = nf * 16 + m;
    #pragma unroll
    for (int j = 0; j < 4; ++j) {
      int r = crow0 + j;
      if (r < nrows) {
        float v = acc[nf][j];
        if (RELU) v = fmaxf(v, 0.f);
        if (OUT_BF16)
          ((unsigned short*)Cout)[(size_t)r * 128 + col] = (unsigned short)f2bf(v);
        else
          ((float*)Cout)[(size_t)r * 128 + col] = v;
      }
    }
  }
}

// ---------------- launch ----------------

extern "C" void kernel_launch(void* const* d_in, const int* in_sizes, int n_in,
                              void* d_out, int out_size, void* d_ws, size_t ws_size,
                              hipStream_t stream) {
  const float* x = (const float*)d_in[0];
  const float* wn1 = (const float*)d_in[1];
  const float* wr1 = (const float*)d_in[2];
  const float* wn2 = (const float*)d_in[3];
  const float* wr2 = (const float*)d_in[4];
  const int* ei = (const int*)d_in[5];
  const int N = in_sizes[0] / 128;
  const int E = in_sizes[5] / 2;
  const int* row = ei;      // destinations
  const int* col = ei + E;  // sources
  const int NBUK = (N + 255) >> 8;

  char* p = (char*)d_ws;
  unsigned short* Xb = (unsigned short*)p;  p += (size_t)N * 128 * 2;  // 25.6 MB
  unsigned short* Hb = (unsigned short*)p;  p += (size_t)N * 128 * 2;  // 25.6 MB
  int* bbuf = (int*)p;      p += (size_t)E * 4;                        // 6.4 MB
  int* colidx = (int*)p;    p += (size_t)E * 4;                        // 6.4 MB
  int* rowptr = (int*)p;    p += (size_t)(N + 1) * 4;
  int* deg = (int*)p;       p += (size_t)N * 4;
  float* invdeg = (float*)p; p += (size_t)N * 4;
  int* bcount = (int*)p;    p += NBUK_MAX * 4;
  int* boff = (int*)p;      p += (NBUK_MAX + 1) * 4;
  int* bfill = (int*)p;     p += NBUK_MAX * 4;
  int* bsum = (int*)p;      p += 1024;
  unsigned short* Wb = (unsigned short*)p;  p += 4 * 16384 * 2;  // 128 KB bf16 weights
  unsigned short* Wn1b = Wb;
  unsigned short* Wr1b = Wb + 16384;
  unsigned short* Wn2b = Wb + 2 * 16384;
  unsigned short* Wr2b = Wb + 3 * 16384;
  float* aggbuf = (float*)d_out;  // d_out doubles as f32 aggregation scratch

  // --- CSR build (two-level bucket sort) ---
  hipMemsetAsync(bcount, 0, NBUK * 4, stream);
  p1a_hist<<<256, 256, 0, stream>>>(row, bcount, E, NBUK);
  bucket_scan_kernel<<<1, 512, 0, stream>>>(bcount, boff, bfill, NBUK, E);
  p1c_scatter<<<(E + 256 * P1C_KE - 1) / (256 * P1C_KE), 256, 0, stream>>>(
      row, col, bfill, bbuf, E, NBUK);
  p2a_deg<<<NBUK, 256, 0, stream>>>(boff, bbuf, deg, invdeg, N);
  int nb = (N + 1023) / 1024;
  scan_block_kernel<<<nb, 1024, 0, stream>>>(deg, rowptr, bsum, N);
  scan_sums_kernel<<<1, 64, 0, stream>>>(bsum, nb);
  apply_off_kernel<<<(N + 255) / 256, 256, 0, stream>>>(rowptr, bsum, N, E);
  p2b_place<<<NBUK, 256, 0, stream>>>(boff, bbuf, rowptr, colidx, N);

  // --- conversions ---
  tobf16_kernel<<<2048, 256, 0, stream>>>(x, Xb, (long)N * 32);
  wconv_kernel<<<256, 256, 0, stream>>>(wn1, wr1, wn2, wr2, Wb);

  // --- layer 1: h = relu(agg(x)@Wn1^T + x@Wr1^T), stored bf16 ---
  agg_bf16_kernel<<<(N + 3) / 4, 256, 0, stream>>>(Xb, rowptr, colidx, invdeg,
                                                   aggbuf, N);
  mfma_gemm_kernel<true, true><<<(N + 63) / 64, 256, 0, stream>>>(
      aggbuf, Xb, Wn1b, Wr1b, Hb, N);

  // --- layer 2: out = agg(h)@Wn2^T + h@Wr2^T (f32, in-place per-row on d_out) ---
  agg_bf16_kernel<<<(N + 3) / 4, 256, 0, stream>>>(Hb, rowptr, colidx, invdeg,
                                                   aggbuf, N);
  mfma_gemm_kernel<false, false><<<(N + 63) / 64, 256, 0, stream>>>(
      aggbuf, Hb, Wn2b, Wr2b, (void*)d_out, N);
}

// Round 4
// 275.648 us; speedup vs baseline: 2.3390x; 1.2688x over previous
//
#include <hip/hip_runtime.h>

#define NBUK_MAX 512  // buckets of 256 rows; N=100000 -> 391 buckets

typedef __attribute__((ext_vector_type(8))) short bf16x8;
typedef __attribute__((ext_vector_type(4))) float f32x4;

static __device__ __forceinline__ float bf2f(unsigned int u16) {
  unsigned int t = u16 << 16;
  return __builtin_bit_cast(float, t);
}
static __device__ __forceinline__ unsigned int f2bf(float f) {
  unsigned int t = __builtin_bit_cast(unsigned int, f);
  t += 0x7fff + ((t >> 16) & 1);
  return t >> 16;
}

// ---------------- CSR build: two-level bucket sort ----------------

__global__ __launch_bounds__(256) void p1a_hist(const int* __restrict__ row,
                                                int* __restrict__ bcount, int E,
                                                int nbuk) {
  __shared__ int h[NBUK_MAX];
  for (int i = threadIdx.x; i < nbuk; i += 256) h[i] = 0;
  __syncthreads();
  int stride = gridDim.x * 256;
  for (int e = blockIdx.x * 256 + threadIdx.x; e < E; e += stride)
    atomicAdd(&h[row[e] >> 8], 1);
  __syncthreads();
  for (int i = threadIdx.x; i < nbuk; i += 256)
    if (h[i]) atomicAdd(&bcount[i], h[i]);
}

__global__ __launch_bounds__(512) void bucket_scan_kernel(
    const int* __restrict__ bcount, int* __restrict__ boff,
    int* __restrict__ bfill, int nbuk, int E) {
  __shared__ int s[512];
  int t = threadIdx.x;
  int v = (t < nbuk) ? bcount[t] : 0;
  s[t] = v;
  __syncthreads();
  for (int off = 1; off < 512; off <<= 1) {
    int u = (t >= off) ? s[t - off] : 0;
    __syncthreads();
    s[t] += u;
    __syncthreads();
  }
  if (t < nbuk) {
    int ex = s[t] - v;
    boff[t] = ex;
    bfill[t] = ex;
  }
  if (t == 0) boff[nbuk] = E;
}

#define P1C_KE 32
__global__ __launch_bounds__(256) void p1c_scatter(
    const int* __restrict__ row, const int* __restrict__ col,
    int* __restrict__ bfill, int* __restrict__ bbuf, int E, int nbuk) {
  __shared__ int cnt[NBUK_MAX];
  __shared__ int base[NBUK_MAX];
  int e0 = blockIdx.x * (256 * P1C_KE);
  for (int i = threadIdx.x; i < nbuk; i += 256) cnt[i] = 0;
  __syncthreads();
  for (int k = 0; k < P1C_KE; ++k) {
    int e = e0 + k * 256 + threadIdx.x;
    if (e < E) atomicAdd(&cnt[row[e] >> 8], 1);
  }
  __syncthreads();
  for (int i = threadIdx.x; i < nbuk; i += 256) {
    int c = cnt[i];
    base[i] = c ? atomicAdd(&bfill[i], c) : 0;
    cnt[i] = 0;
  }
  __syncthreads();
  for (int k = 0; k < P1C_KE; ++k) {
    int e = e0 + k * 256 + threadIdx.x;
    if (e < E) {
      int r = row[e];
      int b = r >> 8;
      int rk = atomicAdd(&cnt[b], 1);
      bbuf[base[b] + rk] = ((r & 255) << 17) | col[e];
    }
  }
}

__global__ __launch_bounds__(256) void p2a_deg(const int* __restrict__ boff,
                                               const int* __restrict__ bbuf,
                                               int* __restrict__ deg,
                                               float* __restrict__ invdeg, int N) {
  __shared__ int cnt[256];
  int b = blockIdx.x;
  cnt[threadIdx.x] = 0;
  __syncthreads();
  int s = boff[b], e = boff[b + 1];
  for (int i = s + threadIdx.x; i < e; i += 256) atomicAdd(&cnt[bbuf[i] >> 17], 1);
  __syncthreads();
  int r = (b << 8) + threadIdx.x;
  if (r < N) {
    int c = cnt[threadIdx.x];
    deg[r] = c;
    invdeg[r] = c ? 1.0f / (float)c : 0.0f;
  }
}

__global__ __launch_bounds__(1024) void scan_block_kernel(
    const int* __restrict__ deg, int* __restrict__ rowptr, int* __restrict__ bsum,
    int n) {
  __shared__ int s[1024];
  int i = blockIdx.x * 1024 + threadIdx.x;
  int v = (i < n) ? deg[i] : 0;
  s[threadIdx.x] = v;
  __syncthreads();
  for (int off = 1; off < 1024; off <<= 1) {
    int t = (threadIdx.x >= off) ? s[threadIdx.x - off] : 0;
    __syncthreads();
    s[threadIdx.x] += t;
    __syncthreads();
  }
  if (i < n) rowptr[i] = s[threadIdx.x] - v;  // exclusive within block
  if (threadIdx.x == 1023) bsum[blockIdx.x] = s[1023];
}

__global__ void scan_sums_kernel(int* bsum, int nb) {
  int lane = threadIdx.x;
  int run = 0;
  for (int base = 0; base < nb; base += 64) {
    int orig = (base + lane < nb) ? bsum[base + lane] : 0;
    int v = orig;
    #pragma unroll
    for (int off = 1; off < 64; off <<= 1) {
      int t = __shfl_up(v, off, 64);
      if (lane >= off) v += t;
    }
    if (base + lane < nb) bsum[base + lane] = run + v - orig;
    run += __shfl(v, 63, 64);
  }
}

__global__ void apply_off_kernel(int* __restrict__ rowptr,
                                 const int* __restrict__ bsum, int n, int E) {
  int i = blockIdx.x * blockDim.x + threadIdx.x;
  if (i < n) rowptr[i] += bsum[i >> 10];
  if (i == 0) rowptr[n] = E;
}

__global__ __launch_bounds__(256) void p2b_place(const int* __restrict__ boff,
                                                 const int* __restrict__ bbuf,
                                                 const int* __restrict__ rowptr,
                                                 int* __restrict__ colidx, int N) {
  __shared__ int rbase[256];
  __shared__ int cnt[256];
  int b = blockIdx.x;
  int r = (b << 8) + threadIdx.x;
  rbase[threadIdx.x] = (r < N) ? rowptr[r] : 0;
  cnt[threadIdx.x] = 0;
  __syncthreads();
  int s = boff[b], e = boff[b + 1];
  for (int i = s + threadIdx.x; i < e; i += 256) {
    int p = bbuf[i];
    int rl = p >> 17;
    int k = atomicAdd(&cnt[rl], 1);
    colidx[rbase[rl] + k] = p & 0x1FFFF;
  }
}

// ---------------- conversions ----------------

__global__ __launch_bounds__(256) void tobf16_kernel(const float* __restrict__ in,
                                                     unsigned short* __restrict__ out,
                                                     long n4) {
  long i = (long)blockIdx.x * 256 + threadIdx.x;
  long stride = (long)gridDim.x * 256;
  for (; i < n4; i += stride) {
    float4 v = ((const float4*)in)[i];
    ushort4 o;
    o.x = (unsigned short)f2bf(v.x);
    o.y = (unsigned short)f2bf(v.y);
    o.z = (unsigned short)f2bf(v.z);
    o.w = (unsigned short)f2bf(v.w);
    ((ushort4*)out)[i] = o;
  }
}

// Pack weights fragment-major: Wpack[layer][ks][nf][lane][j] so a wave's
// B-fragment load is one contiguous 1KB global_load_dwordx4.
// Element = W[n = nf*16 + (lane&15)][k = (ks&3)*32 + (lane>>4)*8 + j],
// W = (ks<4 ? Wn : Wr) of that layer. Matches round-3 verified layout.
__global__ __launch_bounds__(256) void wpack_kernel(
    const float* __restrict__ wn1, const float* __restrict__ wr1,
    const float* __restrict__ wn2, const float* __restrict__ wr2,
    unsigned short* __restrict__ out) {
  int i = blockIdx.x * 256 + threadIdx.x;  // 0..65535
  int layer = i >> 15;
  int r = i & 32767;
  int ks = r >> 12;
  int nf = (r >> 9) & 7;
  int lane = (r >> 3) & 63;
  int j = r & 7;
  const float* src = layer ? ((ks < 4) ? wn2 : wr2) : ((ks < 4) ? wn1 : wr1);
  int m = lane & 15, kgrp = lane >> 4;
  int kk = (ks & 3) * 32 + kgrp * 8 + j;
  int n = nf * 16 + m;
  out[i] = (unsigned short)f2bf(src[n * 128 + kk]);
}

// ---------------- mean aggregation (bf16 gather, f32 accum, bf16 out) ----------------

__global__ __launch_bounds__(256) void agg_bf16_kernel(
    const unsigned short* __restrict__ feat, const int* __restrict__ rowptr,
    const int* __restrict__ colidx, const float* __restrict__ invdeg,
    unsigned short* __restrict__ out, int n) {
  int node = blockIdx.x * 4 + (threadIdx.x >> 6);
  int lane = threadIdx.x & 63;
  if (node >= n) return;
  int start = rowptr[node], end = rowptr[node + 1];
  float ax = 0.f, ay = 0.f;
  for (int base = start; base < end; base += 64) {
    int cnt = end - base;
    if (cnt > 64) cnt = 64;
    int cidx = (base + lane < end) ? colidx[base + lane] : 0;
    int t = 0;
    for (; t + 4 <= cnt; t += 4) {
      int c0 = __shfl(cidx, t + 0, 64);
      int c1 = __shfl(cidx, t + 1, 64);
      int c2 = __shfl(cidx, t + 2, 64);
      int c3 = __shfl(cidx, t + 3, 64);
      unsigned int v0 = *(const unsigned int*)(feat + (size_t)c0 * 128 + lane * 2);
      unsigned int v1 = *(const unsigned int*)(feat + (size_t)c1 * 128 + lane * 2);
      unsigned int v2 = *(const unsigned int*)(feat + (size_t)c2 * 128 + lane * 2);
      unsigned int v3 = *(const unsigned int*)(feat + (size_t)c3 * 128 + lane * 2);
      ax += bf2f(v0 & 0xffff) + bf2f(v1 & 0xffff) + bf2f(v2 & 0xffff) +
            bf2f(v3 & 0xffff);
      ay += bf2f(v0 >> 16) + bf2f(v1 >> 16) + bf2f(v2 >> 16) + bf2f(v3 >> 16);
    }
    for (; t < cnt; ++t) {
      int c = __shfl(cidx, t, 64);
      unsigned int v = *(const unsigned int*)(feat + (size_t)c * 128 + lane * 2);
      ax += bf2f(v & 0xffff);
      ay += bf2f(v >> 16);
    }
  }
  float s = invdeg[node];
  unsigned int pk = f2bf(ax * s) | (f2bf(ay * s) << 16);
  *(unsigned int*)(out + (size_t)node * 128 + lane * 2) = pk;
}

// ---------------- MFMA dual-GEMM: C = Aagg@Wn^T + Aroot@Wr^T (+ReLU) ----------------
// Block: 256 thr = 4 waves; block tile 64 rows x 128 cols; wave tile 16x128.
// All operands bf16; A-frags (8) hoisted; B-frags from fragment-major Wpack
// (one contiguous 1KB load per fragment, L2-resident).
// C/D: col = lane&15, row = (lane>>4)*4 + reg  (verified m89/m91 mapping).

template <bool RELU, bool OUT_BF16>
__global__ __launch_bounds__(256) void mfma_gemm_kernel(
    const unsigned short* __restrict__ Aagg,   // bf16 [nrows][128]
    const unsigned short* __restrict__ Aroot,  // bf16 [nrows][128]
    const unsigned short* __restrict__ Wpack,  // bf16 [8][8][64][8] frag-major
    void* __restrict__ Cout, int nrows) {
  const int lane = threadIdx.x & 63;
  const int wid = threadIdx.x >> 6;
  const int row0 = blockIdx.x * 64 + wid * 16;
  const int m = lane & 15;
  const int kgrp = lane >> 4;  // 0..3
  int arow = row0 + m;
  if (arow > nrows - 1) arow = nrows - 1;  // clamp; stores masked

  bf16x8 a[8];
  #pragma unroll
  for (int ks = 0; ks < 4; ++ks)
    a[ks] = *(const bf16x8*)(Aagg + (size_t)arow * 128 + ks * 32 + kgrp * 8);
  #pragma unroll
  for (int ks = 4; ks < 8; ++ks)
    a[ks] = *(const bf16x8*)(Aroot + (size_t)arow * 128 + (ks - 4) * 32 + kgrp * 8);

  f32x4 acc[8];
  #pragma unroll
  for (int i = 0; i < 8; ++i) acc[i] = (f32x4){0.f, 0.f, 0.f, 0.f};

  const unsigned short* wp = Wpack + (size_t)lane * 8;
  #pragma unroll
  for (int ks = 0; ks < 8; ++ks) {
    #pragma unroll
    for (int nf = 0; nf < 8; ++nf) {
      bf16x8 b = *(const bf16x8*)(wp + ((ks * 8 + nf) << 9));
      acc[nf] = __builtin_amdgcn_mfma_f32_16x16x32_bf16(a[ks], b, acc[nf], 0, 0, 0);
    }
  }

  const int crow0 = row0 + kgrp * 4;
  #pragma unroll
  for (int nf = 0; nf < 8; ++nf) {
    int col = nf * 16 + m;
    #pragma unroll
    for (int j = 0; j < 4; ++j) {
      int r = crow0 + j;
      if (r < nrows) {
        float v = acc[nf][j];
        if (RELU) v = fmaxf(v, 0.f);
        if (OUT_BF16)
          ((unsigned short*)Cout)[(size_t)r * 128 + col] = (unsigned short)f2bf(v);
        else
          ((float*)Cout)[(size_t)r * 128 + col] = v;
      }
    }
  }
}

// ---------------- launch ----------------

extern "C" void kernel_launch(void* const* d_in, const int* in_sizes, int n_in,
                              void* d_out, int out_size, void* d_ws, size_t ws_size,
                              hipStream_t stream) {
  const float* x = (const float*)d_in[0];
  const float* wn1 = (const float*)d_in[1];
  const float* wr1 = (const float*)d_in[2];
  const float* wn2 = (const float*)d_in[3];
  const float* wr2 = (const float*)d_in[4];
  const int* ei = (const int*)d_in[5];
  const int N = in_sizes[0] / 128;
  const int E = in_sizes[5] / 2;
  const int* row = ei;      // destinations
  const int* col = ei + E;  // sources
  const int NBUK = (N + 255) >> 8;

  char* p = (char*)d_ws;
  unsigned short* Xb = (unsigned short*)p;  p += (size_t)N * 128 * 2;  // 25.6 MB
  unsigned short* Hb = (unsigned short*)p;  p += (size_t)N * 128 * 2;  // 25.6 MB
  int* bbuf = (int*)p;      p += (size_t)E * 4;                        // 6.4 MB
  int* colidx = (int*)p;    p += (size_t)E * 4;                        // 6.4 MB
  int* rowptr = (int*)p;    p += (size_t)(N + 1) * 4;
  int* deg = (int*)p;       p += (size_t)N * 4;
  float* invdeg = (float*)p; p += (size_t)N * 4;
  int* bcount = (int*)p;    p += NBUK_MAX * 4;
  int* boff = (int*)p;      p += (NBUK_MAX + 1) * 4;
  int* bfill = (int*)p;     p += NBUK_MAX * 4;
  int* bsum = (int*)p;      p += 1024;
  unsigned short* Wp = (unsigned short*)p;  p += 2 * 32768 * 2;  // 128 KB packed
  unsigned short* Wp1 = Wp;
  unsigned short* Wp2 = Wp + 32768;

  // agg scratch: layer-1 agg lives in d_out's bytes (bf16, 25.6 MB of the
  // 51.2 MB f32 buffer; fully overwritten by the final GEMM). Layer-2 agg
  // reuses Xb (dead after GEMM-1).
  unsigned short* agg1 = (unsigned short*)d_out;
  unsigned short* agg2 = Xb;

  // --- CSR build (two-level bucket sort) ---
  hipMemsetAsync(bcount, 0, NBUK * 4, stream);
  p1a_hist<<<256, 256, 0, stream>>>(row, bcount, E, NBUK);
  bucket_scan_kernel<<<1, 512, 0, stream>>>(bcount, boff, bfill, NBUK, E);
  p1c_scatter<<<(E + 256 * P1C_KE - 1) / (256 * P1C_KE), 256, 0, stream>>>(
      row, col, bfill, bbuf, E, NBUK);
  p2a_deg<<<NBUK, 256, 0, stream>>>(boff, bbuf, deg, invdeg, N);
  int nb = (N + 1023) / 1024;
  scan_block_kernel<<<nb, 1024, 0, stream>>>(deg, rowptr, bsum, N);
  scan_sums_kernel<<<1, 64, 0, stream>>>(bsum, nb);
  apply_off_kernel<<<(N + 255) / 256, 256, 0, stream>>>(rowptr, bsum, N, E);
  p2b_place<<<NBUK, 256, 0, stream>>>(boff, bbuf, rowptr, colidx, N);

  // --- conversions ---
  tobf16_kernel<<<2048, 256, 0, stream>>>(x, Xb, (long)N * 32);
  wpack_kernel<<<256, 256, 0, stream>>>(wn1, wr1, wn2, wr2, Wp);

  // --- layer 1: h = relu(agg(x)@Wn1^T + x@Wr1^T), stored bf16 ---
  agg_bf16_kernel<<<(N + 3) / 4, 256, 0, stream>>>(Xb, rowptr, colidx, invdeg,
                                                   agg1, N);
  mfma_gemm_kernel<true, true><<<(N + 63) / 64, 256, 0, stream>>>(
      agg1, Xb, Wp1, Hb, N);

  // --- layer 2: out = agg(h)@Wn2^T + h@Wr2^T (f32 to d_out) ---
  agg_bf16_kernel<<<(N + 3) / 4, 256, 0, stream>>>(Hb, rowptr, colidx, invdeg,
                                                   agg2, N);
  mfma_gemm_kernel<false, false><<<(N + 63) / 64, 256, 0, stream>>>(
      agg2, Hb, Wp2, (void*)d_out, N);
}

// Round 5
// 268.724 us; speedup vs baseline: 2.3993x; 1.0258x over previous
//
#include <hip/hip_runtime.h>

#define NBUK_MAX 512  // buckets of 256 rows; N=100000 -> 391 buckets

typedef __attribute__((ext_vector_type(8))) short bf16x8;
typedef __attribute__((ext_vector_type(4))) float f32x4;

static __device__ __forceinline__ float bf2f(unsigned int u16) {
  unsigned int t = u16 << 16;
  return __builtin_bit_cast(float, t);
}
static __device__ __forceinline__ float bflo(unsigned int u) {
  return __builtin_bit_cast(float, u << 16);
}
static __device__ __forceinline__ float bfhi(unsigned int u) {
  return __builtin_bit_cast(float, u & 0xffff0000u);
}
static __device__ __forceinline__ unsigned int f2bf(float f) {
  unsigned int t = __builtin_bit_cast(unsigned int, f);
  t += 0x7fff + ((t >> 16) & 1);
  return t >> 16;
}

// ---------------- CSR build: two-level bucket sort ----------------

__global__ __launch_bounds__(256) void p1a_hist(const int* __restrict__ row,
                                                int* __restrict__ bcount, int E,
                                                int nbuk) {
  __shared__ int h[NBUK_MAX];
  for (int i = threadIdx.x; i < nbuk; i += 256) h[i] = 0;
  __syncthreads();
  int stride = gridDim.x * 256;
  for (int e = blockIdx.x * 256 + threadIdx.x; e < E; e += stride)
    atomicAdd(&h[row[e] >> 8], 1);
  __syncthreads();
  for (int i = threadIdx.x; i < nbuk; i += 256)
    if (h[i]) atomicAdd(&bcount[i], h[i]);
}

__global__ __launch_bounds__(512) void bucket_scan_kernel(
    const int* __restrict__ bcount, int* __restrict__ boff,
    int* __restrict__ bfill, int nbuk, int E) {
  __shared__ int s[512];
  int t = threadIdx.x;
  int v = (t < nbuk) ? bcount[t] : 0;
  s[t] = v;
  __syncthreads();
  for (int off = 1; off < 512; off <<= 1) {
    int u = (t >= off) ? s[t - off] : 0;
    __syncthreads();
    s[t] += u;
    __syncthreads();
  }
  if (t < nbuk) {
    int ex = s[t] - v;
    boff[t] = ex;
    bfill[t] = ex;
  }
  if (t == 0) boff[nbuk] = E;
}

#define P1C_KE 32
__global__ __launch_bounds__(256) void p1c_scatter(
    const int* __restrict__ row, const int* __restrict__ col,
    int* __restrict__ bfill, int* __restrict__ bbuf, int E, int nbuk) {
  __shared__ int cnt[NBUK_MAX];
  __shared__ int base[NBUK_MAX];
  int e0 = blockIdx.x * (256 * P1C_KE);
  for (int i = threadIdx.x; i < nbuk; i += 256) cnt[i] = 0;
  __syncthreads();
  for (int k = 0; k < P1C_KE; ++k) {
    int e = e0 + k * 256 + threadIdx.x;
    if (e < E) atomicAdd(&cnt[row[e] >> 8], 1);
  }
  __syncthreads();
  for (int i = threadIdx.x; i < nbuk; i += 256) {
    int c = cnt[i];
    base[i] = c ? atomicAdd(&bfill[i], c) : 0;
    cnt[i] = 0;
  }
  __syncthreads();
  for (int k = 0; k < P1C_KE; ++k) {
    int e = e0 + k * 256 + threadIdx.x;
    if (e < E) {
      int r = row[e];
      int b = r >> 8;
      int rk = atomicAdd(&cnt[b], 1);
      bbuf[base[b] + rk] = ((r & 255) << 17) | col[e];
    }
  }
}

__global__ __launch_bounds__(256) void p2a_deg(const int* __restrict__ boff,
                                               const int* __restrict__ bbuf,
                                               int* __restrict__ deg,
                                               float* __restrict__ invdeg, int N) {
  __shared__ int cnt[256];
  int b = blockIdx.x;
  cnt[threadIdx.x] = 0;
  __syncthreads();
  int s = boff[b], e = boff[b + 1];
  for (int i = s + threadIdx.x; i < e; i += 256) atomicAdd(&cnt[bbuf[i] >> 17], 1);
  __syncthreads();
  int r = (b << 8) + threadIdx.x;
  if (r < N) {
    int c = cnt[threadIdx.x];
    deg[r] = c;
    invdeg[r] = c ? 1.0f / (float)c : 0.0f;
  }
}

__global__ __launch_bounds__(1024) void scan_block_kernel(
    const int* __restrict__ deg, int* __restrict__ rowptr, int* __restrict__ bsum,
    int n) {
  __shared__ int s[1024];
  int i = blockIdx.x * 1024 + threadIdx.x;
  int v = (i < n) ? deg[i] : 0;
  s[threadIdx.x] = v;
  __syncthreads();
  for (int off = 1; off < 1024; off <<= 1) {
    int t = (threadIdx.x >= off) ? s[threadIdx.x - off] : 0;
    __syncthreads();
    s[threadIdx.x] += t;
    __syncthreads();
  }
  if (i < n) rowptr[i] = s[threadIdx.x] - v;  // exclusive within block
  if (threadIdx.x == 1023) bsum[blockIdx.x] = s[1023];
}

__global__ void scan_sums_kernel(int* bsum, int nb) {
  int lane = threadIdx.x;
  int run = 0;
  for (int base = 0; base < nb; base += 64) {
    int orig = (base + lane < nb) ? bsum[base + lane] : 0;
    int v = orig;
    #pragma unroll
    for (int off = 1; off < 64; off <<= 1) {
      int t = __shfl_up(v, off, 64);
      if (lane >= off) v += t;
    }
    if (base + lane < nb) bsum[base + lane] = run + v - orig;
    run += __shfl(v, 63, 64);
  }
}

__global__ void apply_off_kernel(int* __restrict__ rowptr,
                                 const int* __restrict__ bsum, int n, int E) {
  int i = blockIdx.x * blockDim.x + threadIdx.x;
  if (i < n) rowptr[i] += bsum[i >> 10];
  if (i == 0) rowptr[n] = E;
}

__global__ __launch_bounds__(256) void p2b_place(const int* __restrict__ boff,
                                                 const int* __restrict__ bbuf,
                                                 const int* __restrict__ rowptr,
                                                 int* __restrict__ colidx, int N) {
  __shared__ int rbase[256];
  __shared__ int cnt[256];
  int b = blockIdx.x;
  int r = (b << 8) + threadIdx.x;
  rbase[threadIdx.x] = (r < N) ? rowptr[r] : 0;
  cnt[threadIdx.x] = 0;
  __syncthreads();
  int s = boff[b], e = boff[b + 1];
  for (int i = s + threadIdx.x; i < e; i += 256) {
    int p = bbuf[i];
    int rl = p >> 17;
    int k = atomicAdd(&cnt[rl], 1);
    colidx[rbase[rl] + k] = p & 0x1FFFF;
  }
}

// ---------------- conversions ----------------

__global__ __launch_bounds__(256) void tobf16_kernel(const float* __restrict__ in,
                                                     unsigned short* __restrict__ out,
                                                     long n4) {
  long i = (long)blockIdx.x * 256 + threadIdx.x;
  long stride = (long)gridDim.x * 256;
  for (; i < n4; i += stride) {
    float4 v = ((const float4*)in)[i];
    ushort4 o;
    o.x = (unsigned short)f2bf(v.x);
    o.y = (unsigned short)f2bf(v.y);
    o.z = (unsigned short)f2bf(v.z);
    o.w = (unsigned short)f2bf(v.w);
    ((ushort4*)out)[i] = o;
  }
}

// Pack weights fragment-major: Wpack[layer][ks][nf][lane][j] so a wave's
// B-fragment load is one contiguous 1KB global_load_dwordx4.
// Element = W[n = nf*16 + (lane&15)][k = (ks&3)*32 + (lane>>4)*8 + j],
// W = (ks<4 ? Wn : Wr) of that layer. Matches round-3 verified layout.
__global__ __launch_bounds__(256) void wpack_kernel(
    const float* __restrict__ wn1, const float* __restrict__ wr1,
    const float* __restrict__ wn2, const float* __restrict__ wr2,
    unsigned short* __restrict__ out) {
  int i = blockIdx.x * 256 + threadIdx.x;  // 0..65535
  int layer = i >> 15;
  int r = i & 32767;
  int ks = r >> 12;
  int nf = (r >> 9) & 7;
  int lane = (r >> 3) & 63;
  int j = r & 7;
  const float* src = layer ? ((ks < 4) ? wn2 : wr2) : ((ks < 4) ? wn1 : wr1);
  int m = lane & 15, kgrp = lane >> 4;
  int kk = (ks & 3) * 32 + kgrp * 8 + j;
  int n = nf * 16 + m;
  out[i] = (unsigned short)f2bf(src[n * 128 + kk]);
}

// ---------------- mean aggregation ----------------
// Wave = 4 edge-slots (groups of 16 lanes) x 16 feature-lanes (8 feats each,
// uint4 = 16B per lane). One dwordx4 wave-load gathers 4 edges (1KB); two
// issued per iteration (8 edges, 2KB in flight). One ds_bpermute broadcasts
// all 4 edge indices. Cross-group reduce via shfl_xor(16/32) once per node.

__global__ __launch_bounds__(256) void agg_bf16_kernel(
    const unsigned short* __restrict__ feat, const int* __restrict__ rowptr,
    const int* __restrict__ colidx, const float* __restrict__ invdeg,
    unsigned short* __restrict__ out, int n) {
  int node = blockIdx.x * 4 + (threadIdx.x >> 6);
  int lane = threadIdx.x & 63;
  if (node >= n) return;
  const int g = lane >> 4;   // edge-slot 0..3
  const int fl = lane & 15;  // features fl*8 .. fl*8+7
  int start = rowptr[node], end = rowptr[node + 1];

  float acc[8];
  #pragma unroll
  for (int j = 0; j < 8; ++j) acc[j] = 0.f;

  for (int base = start; base < end; base += 64) {
    int cnt = end - base;
    if (cnt > 64) cnt = 64;
    int cidx = (base + lane < end) ? colidx[base + lane] : 0;
    for (int t = 0; t < cnt; t += 8) {
      int i0 = t + g, i1 = t + 4 + g;
      int c0 = __shfl(cidx, i0, 64);
      int c1 = __shfl(cidx, i1, 64);
      uint4 v0 = make_uint4(0u, 0u, 0u, 0u);
      uint4 v1 = make_uint4(0u, 0u, 0u, 0u);
      if (i0 < cnt) v0 = *(const uint4*)(feat + (size_t)c0 * 128 + fl * 8);
      if (i1 < cnt) v1 = *(const uint4*)(feat + (size_t)c1 * 128 + fl * 8);
      acc[0] += bflo(v0.x) + bflo(v1.x);
      acc[1] += bfhi(v0.x) + bfhi(v1.x);
      acc[2] += bflo(v0.y) + bflo(v1.y);
      acc[3] += bfhi(v0.y) + bfhi(v1.y);
      acc[4] += bflo(v0.z) + bflo(v1.z);
      acc[5] += bfhi(v0.z) + bfhi(v1.z);
      acc[6] += bflo(v0.w) + bflo(v1.w);
      acc[7] += bfhi(v0.w) + bfhi(v1.w);
    }
  }

  // reduce the 4 edge-slot groups (lane ^16, ^32 hold same features)
  #pragma unroll
  for (int j = 0; j < 8; ++j) {
    acc[j] += __shfl_xor(acc[j], 16, 64);
    acc[j] += __shfl_xor(acc[j], 32, 64);
  }

  if (g == 0) {
    float s = invdeg[node];
    uint4 pk;
    pk.x = f2bf(acc[0] * s) | (f2bf(acc[1] * s) << 16);
    pk.y = f2bf(acc[2] * s) | (f2bf(acc[3] * s) << 16);
    pk.z = f2bf(acc[4] * s) | (f2bf(acc[5] * s) << 16);
    pk.w = f2bf(acc[6] * s) | (f2bf(acc[7] * s) << 16);
    *(uint4*)(out + (size_t)node * 128 + fl * 8) = pk;
  }
}

// ---------------- MFMA dual-GEMM: C = Aagg@Wn^T + Aroot@Wr^T (+ReLU) ----------------
// Block: 256 thr = 4 waves; block tile 64 rows x 128 cols; wave tile 16x128.
// All operands bf16; A-frags (8) hoisted; B-frags from fragment-major Wpack
// (one contiguous 1KB load per fragment, L2-resident).
// C/D: col = lane&15, row = (lane>>4)*4 + reg  (verified m89/m91 mapping).

template <bool RELU, bool OUT_BF16>
__global__ __launch_bounds__(256) void mfma_gemm_kernel(
    const unsigned short* __restrict__ Aagg,   // bf16 [nrows][128]
    const unsigned short* __restrict__ Aroot,  // bf16 [nrows][128]
    const unsigned short* __restrict__ Wpack,  // bf16 [8][8][64][8] frag-major
    void* __restrict__ Cout, int nrows) {
  const int lane = threadIdx.x & 63;
  const int wid = threadIdx.x >> 6;
  const int row0 = blockIdx.x * 64 + wid * 16;
  const int m = lane & 15;
  const int kgrp = lane >> 4;  // 0..3
  int arow = row0 + m;
  if (arow > nrows - 1) arow = nrows - 1;  // clamp; stores masked

  bf16x8 a[8];
  #pragma unroll
  for (int ks = 0; ks < 4; ++ks)
    a[ks] = *(const bf16x8*)(Aagg + (size_t)arow * 128 + ks * 32 + kgrp * 8);
  #pragma unroll
  for (int ks = 4; ks < 8; ++ks)
    a[ks] = *(const bf16x8*)(Aroot + (size_t)arow * 128 + (ks - 4) * 32 + kgrp * 8);

  f32x4 acc[8];
  #pragma unroll
  for (int i = 0; i < 8; ++i) acc[i] = (f32x4){0.f, 0.f, 0.f, 0.f};

  const unsigned short* wp = Wpack + (size_t)lane * 8;
  #pragma unroll
  for (int ks = 0; ks < 8; ++ks) {
    #pragma unroll
    for (int nf = 0; nf < 8; ++nf) {
      bf16x8 b = *(const bf16x8*)(wp + ((ks * 8 + nf) << 9));
      acc[nf] = __builtin_amdgcn_mfma_f32_16x16x32_bf16(a[ks], b, acc[nf], 0, 0, 0);
    }
  }

  const int crow0 = row0 + kgrp * 4;
  #pragma unroll
  for (int nf = 0; nf < 8; ++nf) {
    int col = nf * 16 + m;
    #pragma unroll
    for (int j = 0; j < 4; ++j) {
      int r = crow0 + j;
      if (r < nrows) {
        float v = acc[nf][j];
        if (RELU) v = fmaxf(v, 0.f);
        if (OUT_BF16)
          ((unsigned short*)Cout)[(size_t)r * 128 + col] = (unsigned short)f2bf(v);
        else
          ((float*)Cout)[(size_t)r * 128 + col] = v;
      }
    }
  }
}

// ---------------- launch ----------------

extern "C" void kernel_launch(void* const* d_in, const int* in_sizes, int n_in,
                              void* d_out, int out_size, void* d_ws, size_t ws_size,
                              hipStream_t stream) {
  const float* x = (const float*)d_in[0];
  const float* wn1 = (const float*)d_in[1];
  const float* wr1 = (const float*)d_in[2];
  const float* wn2 = (const float*)d_in[3];
  const float* wr2 = (const float*)d_in[4];
  const int* ei = (const int*)d_in[5];
  const int N = in_sizes[0] / 128;
  const int E = in_sizes[5] / 2;
  const int* row = ei;      // destinations
  const int* col = ei + E;  // sources
  const int NBUK = (N + 255) >> 8;

  char* p = (char*)d_ws;
  unsigned short* Xb = (unsigned short*)p;  p += (size_t)N * 128 * 2;  // 25.6 MB
  unsigned short* Hb = (unsigned short*)p;  p += (size_t)N * 128 * 2;  // 25.6 MB
  int* bbuf = (int*)p;      p += (size_t)E * 4;                        // 6.4 MB
  int* colidx = (int*)p;    p += (size_t)E * 4;                        // 6.4 MB
  int* rowptr = (int*)p;    p += (size_t)(N + 1) * 4;
  int* deg = (int*)p;       p += (size_t)N * 4;
  float* invdeg = (float*)p; p += (size_t)N * 4;
  int* bcount = (int*)p;    p += NBUK_MAX * 4;
  int* boff = (int*)p;      p += (NBUK_MAX + 1) * 4;
  int* bfill = (int*)p;     p += NBUK_MAX * 4;
  int* bsum = (int*)p;      p += 1024;
  unsigned short* Wp = (unsigned short*)p;  p += 2 * 32768 * 2;  // 128 KB packed
  unsigned short* Wp1 = Wp;
  unsigned short* Wp2 = Wp + 32768;

  // agg scratch: layer-1 agg lives in d_out's bytes (bf16, 25.6 MB of the
  // 51.2 MB f32 buffer; fully overwritten by the final GEMM). Layer-2 agg
  // reuses Xb (dead after GEMM-1).
  unsigned short* agg1 = (unsigned short*)d_out;
  unsigned short* agg2 = Xb;

  // --- CSR build (two-level bucket sort) ---
  hipMemsetAsync(bcount, 0, NBUK * 4, stream);
  p1a_hist<<<256, 256, 0, stream>>>(row, bcount, E, NBUK);
  bucket_scan_kernel<<<1, 512, 0, stream>>>(bcount, boff, bfill, NBUK, E);
  p1c_scatter<<<(E + 256 * P1C_KE - 1) / (256 * P1C_KE), 256, 0, stream>>>(
      row, col, bfill, bbuf, E, NBUK);
  p2a_deg<<<NBUK, 256, 0, stream>>>(boff, bbuf, deg, invdeg, N);
  int nb = (N + 1023) / 1024;
  scan_block_kernel<<<nb, 1024, 0, stream>>>(deg, rowptr, bsum, N);
  scan_sums_kernel<<<1, 64, 0, stream>>>(bsum, nb);
  apply_off_kernel<<<(N + 255) / 256, 256, 0, stream>>>(rowptr, bsum, N, E);
  p2b_place<<<NBUK, 256, 0, stream>>>(boff, bbuf, rowptr, colidx, N);

  // --- conversions ---
  tobf16_kernel<<<2048, 256, 0, stream>>>(x, Xb, (long)N * 32);
  wpack_kernel<<<256, 256, 0, stream>>>(wn1, wr1, wn2, wr2, Wp);

  // --- layer 1: h = relu(agg(x)@Wn1^T + x@Wr1^T), stored bf16 ---
  agg_bf16_kernel<<<(N + 3) / 4, 256, 0, stream>>>(Xb, rowptr, colidx, invdeg,
                                                   agg1, N);
  mfma_gemm_kernel<true, true><<<(N + 63) / 64, 256, 0, stream>>>(
      agg1, Xb, Wp1, Hb, N);

  // --- layer 2: out = agg(h)@Wn2^T + h@Wr2^T (f32 to d_out) ---
  agg_bf16_kernel<<<(N + 3) / 4, 256, 0, stream>>>(Hb, rowptr, colidx, invdeg,
                                                   agg2, N);
  mfma_gemm_kernel<false, false><<<(N + 63) / 64, 256, 0, stream>>>(
      agg2, Hb, Wp2, (void*)d_out, N);
}

// Round 6
// 260.393 us; speedup vs baseline: 2.4760x; 1.0320x over previous
//
#include <hip/hip_runtime.h>

#define NBUK_MAX 2048  // buckets of 64 rows; N=100000 -> 1563 buckets
#define BNODE 64       // nodes per bucket
#define AGG_CAP 1536   // LDS sorted-col capacity (mean 1024, sigma 32)

typedef __attribute__((ext_vector_type(8))) short bf16x8;
typedef __attribute__((ext_vector_type(4))) float f32x4;

static __device__ __forceinline__ float bflo(unsigned int u) {
  return __builtin_bit_cast(float, u << 16);
}
static __device__ __forceinline__ float bfhi(unsigned int u) {
  return __builtin_bit_cast(float, u & 0xffff0000u);
}
static __device__ __forceinline__ unsigned int f2bf(float f) {
  unsigned int t = __builtin_bit_cast(unsigned int, f);
  t += 0x7fff + ((t >> 16) & 1);
  return t >> 16;
}

// ---------------- bucket sort (phase 1 only; phase 2 fused into agg) --------

__global__ __launch_bounds__(256) void p1a_hist(const int* __restrict__ row,
                                                int* __restrict__ bcount, int E,
                                                int nbuk) {
  __shared__ int h[NBUK_MAX];
  for (int i = threadIdx.x; i < nbuk; i += 256) h[i] = 0;
  __syncthreads();
  int stride = gridDim.x * 256;
  for (int e = blockIdx.x * 256 + threadIdx.x; e < E; e += stride)
    atomicAdd(&h[row[e] >> 6], 1);
  __syncthreads();
  for (int i = threadIdx.x; i < nbuk; i += 256)
    if (h[i]) atomicAdd(&bcount[i], h[i]);
}

__global__ __launch_bounds__(1024) void bucket_scan_kernel(
    const int* __restrict__ bcount, int* __restrict__ boff,
    int* __restrict__ bfill, int nbuk, int E) {
  __shared__ int s[1024];
  int carry = 0;
  int t = threadIdx.x;
  for (int base = 0; base < nbuk; base += 1024) {
    int v = (base + t < nbuk) ? bcount[base + t] : 0;
    s[t] = v;
    __syncthreads();
    for (int off = 1; off < 1024; off <<= 1) {
      int u = (t >= off) ? s[t - off] : 0;
      __syncthreads();
      s[t] += u;
      __syncthreads();
    }
    if (base + t < nbuk) {
      int ex = carry + s[t] - v;
      boff[base + t] = ex;
      bfill[base + t] = ex;
    }
    carry += s[1023];
    __syncthreads();
  }
  if (t == 0) boff[nbuk] = E;
}

#define P1C_KE 32
__global__ __launch_bounds__(256) void p1c_scatter(
    const int* __restrict__ row, const int* __restrict__ col,
    int* __restrict__ bfill, int* __restrict__ bbuf, int E, int nbuk) {
  __shared__ int cnt[NBUK_MAX];
  __shared__ int base[NBUK_MAX];
  int e0 = blockIdx.x * (256 * P1C_KE);
  for (int i = threadIdx.x; i < nbuk; i += 256) cnt[i] = 0;
  __syncthreads();
  for (int k = 0; k < P1C_KE; ++k) {
    int e = e0 + k * 256 + threadIdx.x;
    if (e < E) atomicAdd(&cnt[row[e] >> 6], 1);
  }
  __syncthreads();
  for (int i = threadIdx.x; i < nbuk; i += 256) {
    int c = cnt[i];
    base[i] = c ? atomicAdd(&bfill[i], c) : 0;
    cnt[i] = 0;
  }
  __syncthreads();
  for (int k = 0; k < P1C_KE; ++k) {
    int e = e0 + k * 256 + threadIdx.x;
    if (e < E) {
      int r = row[e];
      int b = r >> 6;
      int rk = atomicAdd(&cnt[b], 1);
      bbuf[base[b] + rk] = ((r & (BNODE - 1)) << 17) | col[e];
    }
  }
}

// ---------------- conversions ----------------

__global__ __launch_bounds__(256) void tobf16_kernel(const float* __restrict__ in,
                                                     unsigned short* __restrict__ out,
                                                     long n4) {
  long i = (long)blockIdx.x * 256 + threadIdx.x;
  long stride = (long)gridDim.x * 256;
  for (; i < n4; i += stride) {
    float4 v = ((const float4*)in)[i];
    ushort4 o;
    o.x = (unsigned short)f2bf(v.x);
    o.y = (unsigned short)f2bf(v.y);
    o.z = (unsigned short)f2bf(v.z);
    o.w = (unsigned short)f2bf(v.w);
    ((ushort4*)out)[i] = o;
  }
}

// Pack weights fragment-major: Wpack[layer][ks][nf][lane][j] (see round 4).
__global__ __launch_bounds__(256) void wpack_kernel(
    const float* __restrict__ wn1, const float* __restrict__ wr1,
    const float* __restrict__ wn2, const float* __restrict__ wr2,
    unsigned short* __restrict__ out) {
  int i = blockIdx.x * 256 + threadIdx.x;  // 0..65535
  int layer = i >> 15;
  int r = i & 32767;
  int ks = r >> 12;
  int nf = (r >> 9) & 7;
  int lane = (r >> 3) & 63;
  int j = r & 7;
  const float* src = layer ? ((ks < 4) ? wn2 : wr2) : ((ks < 4) ? wn1 : wr1);
  int m = lane & 15, kgrp = lane >> 4;
  int kk = (ks & 3) * 32 + kgrp * 8 + j;
  int n = nf * 16 + m;
  out[i] = (unsigned short)f2bf(src[n * 128 + kk]);
}

// ---------------- fused sort + mean aggregation ----------------
// One block per 64-node bucket. Phase A: LDS histogram of the bucket's bbuf
// slice -> deg; wave-scan 64 counters -> start offsets; place sorted col
// indices into LDS (6KB). Phase B: 16 groups of 16 lanes; each group owns 4
// consecutive nodes; per edge one uniform LDS broadcast read + one 16-lane
// uint4 gather (256B coalesced); 4-edge unroll -> 16 gathers in flight/wave.

__global__ __launch_bounds__(256) void agg_fused_kernel(
    const unsigned short* __restrict__ feat, const int* __restrict__ boff,
    const int* __restrict__ bbuf, unsigned short* __restrict__ out, int N) {
  __shared__ int cols[AGG_CAP];
  __shared__ int hist[BNODE];
  __shared__ int startc[BNODE];
  __shared__ int fillc[BNODE];
  const int b = blockIdx.x;
  const int tid = threadIdx.x;
  const int gs = boff[b], ge = boff[b + 1];
  const int bsize = ge - gs;

  if (tid < BNODE) hist[tid] = 0;
  __syncthreads();
  for (int i = gs + tid; i < ge; i += 256)
    atomicAdd(&hist[((unsigned)bbuf[i]) >> 17], 1);
  __syncthreads();
  if (tid < 64) {
    int v = hist[tid];
    int s = v;
    #pragma unroll
    for (int off = 1; off < 64; off <<= 1) {
      int u = __shfl_up(s, off, 64);
      if (tid >= off) s += u;
    }
    startc[tid] = s - v;
    fillc[tid] = s - v;
  }
  __syncthreads();
  const bool fast = (bsize <= AGG_CAP);
  if (fast) {
    for (int i = tid; i < bsize; i += 256) {
      int p = bbuf[gs + i];
      int rl = ((unsigned)p) >> 17;
      int k = atomicAdd(&fillc[rl], 1);
      cols[k] = p & 0x1FFFF;
    }
  }
  __syncthreads();

  const int fl = tid & 15;    // feature lanes: feats fl*8 .. fl*8+7
  const int grp = tid >> 4;   // 0..15, each owns 4 consecutive nodes

  #pragma unroll
  for (int q = 0; q < 4; ++q) {
    const int nl = grp * 4 + q;
    const int node = b * BNODE + nl;
    if (node >= N) continue;
    const int d = hist[nl];
    const int s0 = startc[nl];
    float acc[8];
    #pragma unroll
    for (int j = 0; j < 8; ++j) acc[j] = 0.f;

    if (fast) {
      int k = 0;
      for (; k + 4 <= d; k += 4) {
        int c0 = cols[s0 + k + 0];
        int c1 = cols[s0 + k + 1];
        int c2 = cols[s0 + k + 2];
        int c3 = cols[s0 + k + 3];
        uint4 v0 = *(const uint4*)(feat + (size_t)c0 * 128 + fl * 8);
        uint4 v1 = *(const uint4*)(feat + (size_t)c1 * 128 + fl * 8);
        uint4 v2 = *(const uint4*)(feat + (size_t)c2 * 128 + fl * 8);
        uint4 v3 = *(const uint4*)(feat + (size_t)c3 * 128 + fl * 8);
        acc[0] += bflo(v0.x) + bflo(v1.x) + bflo(v2.x) + bflo(v3.x);
        acc[1] += bfhi(v0.x) + bfhi(v1.x) + bfhi(v2.x) + bfhi(v3.x);
        acc[2] += bflo(v0.y) + bflo(v1.y) + bflo(v2.y) + bflo(v3.y);
        acc[3] += bfhi(v0.y) + bfhi(v1.y) + bfhi(v2.y) + bfhi(v3.y);
        acc[4] += bflo(v0.z) + bflo(v1.z) + bflo(v2.z) + bflo(v3.z);
        acc[5] += bfhi(v0.z) + bfhi(v1.z) + bfhi(v2.z) + bfhi(v3.z);
        acc[6] += bflo(v0.w) + bflo(v1.w) + bflo(v2.w) + bflo(v3.w);
        acc[7] += bfhi(v0.w) + bfhi(v1.w) + bfhi(v2.w) + bfhi(v3.w);
      }
      for (; k < d; ++k) {
        int c = cols[s0 + k];
        uint4 v = *(const uint4*)(feat + (size_t)c * 128 + fl * 8);
        acc[0] += bflo(v.x);
        acc[1] += bfhi(v.x);
        acc[2] += bflo(v.y);
        acc[3] += bfhi(v.y);
        acc[4] += bflo(v.z);
        acc[5] += bfhi(v.z);
        acc[6] += bflo(v.w);
        acc[7] += bfhi(v.w);
      }
    } else {
      // overflow fallback (bucket > AGG_CAP; statistically never for this input)
      for (int i = 0; i < bsize; ++i) {
        int p = bbuf[gs + i];
        if ((((unsigned)p) >> 17) == (unsigned)nl) {
          uint4 v = *(const uint4*)(feat + (size_t)(p & 0x1FFFF) * 128 + fl * 8);
          acc[0] += bflo(v.x);
          acc[1] += bfhi(v.x);
          acc[2] += bflo(v.y);
          acc[3] += bfhi(v.y);
          acc[4] += bflo(v.z);
          acc[5] += bfhi(v.z);
          acc[6] += bflo(v.w);
          acc[7] += bfhi(v.w);
        }
      }
    }

    float inv = (d > 0) ? (1.0f / (float)d) : 0.0f;
    uint4 pk;
    pk.x = f2bf(acc[0] * inv) | (f2bf(acc[1] * inv) << 16);
    pk.y = f2bf(acc[2] * inv) | (f2bf(acc[3] * inv) << 16);
    pk.z = f2bf(acc[4] * inv) | (f2bf(acc[5] * inv) << 16);
    pk.w = f2bf(acc[6] * inv) | (f2bf(acc[7] * inv) << 16);
    *(uint4*)(out + (size_t)node * 128 + fl * 8) = pk;
  }
}

// ---------------- MFMA dual-GEMM: C = Aagg@Wn^T + Aroot@Wr^T (+ReLU) --------
// Unchanged from round 4 (verified). Block tile 64x128, wave tile 16x128,
// frag-major Wpack, C/D: col=lane&15, row=(lane>>4)*4+reg.

template <bool RELU, bool OUT_BF16>
__global__ __launch_bounds__(256) void mfma_gemm_kernel(
    const unsigned short* __restrict__ Aagg,   // bf16 [nrows][128]
    const unsigned short* __restrict__ Aroot,  // bf16 [nrows][128]
    const unsigned short* __restrict__ Wpack,  // bf16 [8][8][64][8] frag-major
    void* __restrict__ Cout, int nrows) {
  const int lane = threadIdx.x & 63;
  const int wid = threadIdx.x >> 6;
  const int row0 = blockIdx.x * 64 + wid * 16;
  const int m = lane & 15;
  const int kgrp = lane >> 4;  // 0..3
  int arow = row0 + m;
  if (arow > nrows - 1) arow = nrows - 1;  // clamp; stores masked

  bf16x8 a[8];
  #pragma unroll
  for (int ks = 0; ks < 4; ++ks)
    a[ks] = *(const bf16x8*)(Aagg + (size_t)arow * 128 + ks * 32 + kgrp * 8);
  #pragma unroll
  for (int ks = 4; ks < 8; ++ks)
    a[ks] = *(const bf16x8*)(Aroot + (size_t)arow * 128 + (ks - 4) * 32 + kgrp * 8);

  f32x4 acc[8];
  #pragma unroll
  for (int i = 0; i < 8; ++i) acc[i] = (f32x4){0.f, 0.f, 0.f, 0.f};

  const unsigned short* wp = Wpack + (size_t)lane * 8;
  #pragma unroll
  for (int ks = 0; ks < 8; ++ks) {
    #pragma unroll
    for (int nf = 0; nf < 8; ++nf) {
      bf16x8 bfr = *(const bf16x8*)(wp + ((ks * 8 + nf) << 9));
      acc[nf] = __builtin_amdgcn_mfma_f32_16x16x32_bf16(a[ks], bfr, acc[nf], 0, 0, 0);
    }
  }

  const int crow0 = row0 + kgrp * 4;
  #pragma unroll
  for (int nf = 0; nf < 8; ++nf) {
    int c = nf * 16 + m;
    #pragma unroll
    for (int j = 0; j < 4; ++j) {
      int r = crow0 + j;
      if (r < nrows) {
        float v = acc[nf][j];
        if (RELU) v = fmaxf(v, 0.f);
        if (OUT_BF16)
          ((unsigned short*)Cout)[(size_t)r * 128 + c] = (unsigned short)f2bf(v);
        else
          ((float*)Cout)[(size_t)r * 128 + c] = v;
      }
    }
  }
}

// ---------------- launch ----------------

extern "C" void kernel_launch(void* const* d_in, const int* in_sizes, int n_in,
                              void* d_out, int out_size, void* d_ws, size_t ws_size,
                              hipStream_t stream) {
  const float* x = (const float*)d_in[0];
  const float* wn1 = (const float*)d_in[1];
  const float* wr1 = (const float*)d_in[2];
  const float* wn2 = (const float*)d_in[3];
  const float* wr2 = (const float*)d_in[4];
  const int* ei = (const int*)d_in[5];
  const int N = in_sizes[0] / 128;
  const int E = in_sizes[5] / 2;
  const int* row = ei;      // destinations
  const int* col = ei + E;  // sources
  const int NBUK = (N + BNODE - 1) / BNODE;  // 1563

  char* p = (char*)d_ws;
  unsigned short* Xb = (unsigned short*)p;  p += (size_t)N * 128 * 2;  // 25.6 MB
  unsigned short* Hb = (unsigned short*)p;  p += (size_t)N * 128 * 2;  // 25.6 MB
  int* bbuf = (int*)p;      p += (size_t)E * 4;                        // 6.4 MB
  int* bcount = (int*)p;    p += NBUK_MAX * 4;
  int* boff = (int*)p;      p += (NBUK_MAX + 1) * 4;
  int* bfill = (int*)p;     p += NBUK_MAX * 4;
  unsigned short* Wp = (unsigned short*)p;  p += 2 * 32768 * 2;  // 128 KB packed
  unsigned short* Wp1 = Wp;
  unsigned short* Wp2 = Wp + 32768;

  // agg scratch: layer-1 agg lives in d_out's bytes (bf16, 25.6 MB of the
  // 51.2 MB f32 buffer; fully overwritten by the final GEMM). Layer-2 agg
  // reuses Xb (dead after GEMM-1).
  unsigned short* agg1 = (unsigned short*)d_out;
  unsigned short* agg2 = Xb;

  // --- bucket sort, phase 1 ---
  hipMemsetAsync(bcount, 0, NBUK * 4, stream);
  p1a_hist<<<256, 256, 0, stream>>>(row, bcount, E, NBUK);
  bucket_scan_kernel<<<1, 1024, 0, stream>>>(bcount, boff, bfill, NBUK, E);
  p1c_scatter<<<(E + 256 * P1C_KE - 1) / (256 * P1C_KE), 256, 0, stream>>>(
      row, col, bfill, bbuf, E, NBUK);

  // --- conversions ---
  tobf16_kernel<<<2048, 256, 0, stream>>>(x, Xb, (long)N * 32);
  wpack_kernel<<<256, 256, 0, stream>>>(wn1, wr1, wn2, wr2, Wp);

  // --- layer 1: h = relu(agg(x)@Wn1^T + x@Wr1^T), stored bf16 ---
  agg_fused_kernel<<<NBUK, 256, 0, stream>>>(Xb, boff, bbuf, agg1, N);
  mfma_gemm_kernel<true, true><<<(N + 63) / 64, 256, 0, stream>>>(
      agg1, Xb, Wp1, Hb, N);

  // --- layer 2: out = agg(h)@Wn2^T + h@Wr2^T (f32 to d_out) ---
  agg_fused_kernel<<<NBUK, 256, 0, stream>>>(Hb, boff, bbuf, agg2, N);
  mfma_gemm_kernel<false, false><<<(N + 63) / 64, 256, 0, stream>>>(
      agg2, Hb, Wp2, (void*)d_out, N);
}